// Round 1
// baseline (752.493 us; speedup 1.0000x reference)
//
#include <hip/hip_runtime.h>
#include <hip/hip_bf16.h>
#include <math.h>

#define B_     32
#define HH_    28
#define WW_    28
#define N_     784
#define C_     384
#define M_     25088      // B_*N_
#define HEADS_ 8
#define HD_    48
#define HID_   1536

typedef __bf16 bf16;
typedef __attribute__((ext_vector_type(8))) __bf16 bf16x8;
typedef __attribute__((ext_vector_type(4))) float f32x4;

// ---------------- weight fp32 -> bf16 ----------------
__global__ void convert_kernel(const float* __restrict__ in, bf16* __restrict__ out, int n) {
    int i = blockIdx.x * 256 + threadIdx.x;
    if (i < n) out[i] = (bf16)in[i];
}

// ---------------- depthwise 3x3 conv + bias + residual (CPE) ----------------
// block = 384 threads (one channel each), grid = M_ spatial positions
__global__ __launch_bounds__(384)
void cpe_kernel(const float* __restrict__ x, const float* __restrict__ w,
                const float* __restrict__ bias, float* __restrict__ y) {
    int row = blockIdx.x;          // b*784 + n
    int c = threadIdx.x;
    int b = row / N_;
    int n = row - b * N_;
    int py = n / WW_, px = n - py * WW_;
    float acc = bias[c];
    #pragma unroll
    for (int ky = 0; ky < 3; ky++) {
        int yy = py + ky - 1;
        if (yy < 0 || yy >= HH_) continue;
        #pragma unroll
        for (int kx = 0; kx < 3; kx++) {
            int xx = px + kx - 1;
            if (xx < 0 || xx >= WW_) continue;
            acc += w[c * 9 + ky * 3 + kx] * x[(size_t)(b * N_ + yy * WW_ + xx) * C_ + c];
        }
    }
    y[(size_t)row * C_ + c] = x[(size_t)row * C_ + c] + acc;
}

// ---------------- layernorm fp32 -> bf16, one wave per row ----------------
__global__ __launch_bounds__(256)
void ln_kernel(const float* __restrict__ x, const float* __restrict__ g,
               const float* __restrict__ beta, bf16* __restrict__ out) {
    int wave = threadIdx.x >> 6;
    int lane = threadIdx.x & 63;
    int row = blockIdx.x * 4 + wave;
    const float* xr = x + (size_t)row * C_;
    float v[6];
    float s = 0.f;
    #pragma unroll
    for (int i = 0; i < 6; i++) { v[i] = xr[lane + i * 64]; s += v[i]; }
    #pragma unroll
    for (int off = 32; off; off >>= 1) s += __shfl_down(s, off, 64);
    s = __shfl(s, 0, 64);
    float mean = s * (1.f / C_);
    float var = 0.f;
    #pragma unroll
    for (int i = 0; i < 6; i++) { float d = v[i] - mean; var += d * d; }
    #pragma unroll
    for (int off = 32; off; off >>= 1) var += __shfl_down(var, off, 64);
    var = __shfl(var, 0, 64);
    float rstd = rsqrtf(var * (1.f / C_) + 1e-5f);
    bf16* orow = out + (size_t)row * C_;
    #pragma unroll
    for (int i = 0; i < 6; i++) {
        int c = lane + i * 64;
        orow[c] = (bf16)((v[i] - mean) * rstd * g[c] + beta[c]);
    }
}

// ---------------- bf16 MFMA GEMM: out[m,n] = act(A[m,:] . W[n,:] + bias[n]) (+resid) ----
// A: M x K bf16 row-major, W: N x K bf16 row-major. 128x128 block tile, BK=32,
// 256 threads = 4 waves in 2x2, each wave 64x64 via 4x4 16x16x32 MFMA tiles.
// Requires M%128==0, N%128==0, K%32==0.
#define LDSTRIDE 40   // 32 + 8 pad: 80B rows -> 2-way bank aliasing (free)
template<bool BIAS, bool GELU, bool RESID, bool OUTBF>
__global__ __launch_bounds__(256)
void gemm_kernel(const bf16* __restrict__ A, const bf16* __restrict__ Wt,
                 const float* __restrict__ bias, const float* __restrict__ resid,
                 void* __restrict__ outp, int M, int N, int K) {
    __shared__ __align__(16) bf16 As[128 * LDSTRIDE];
    __shared__ __align__(16) bf16 Bs[128 * LDSTRIDE];
    const int bm = blockIdx.y * 128, bn = blockIdx.x * 128;
    const int t = threadIdx.x;
    const int wave = t >> 6, lane = t & 63;
    const int wm = (wave & 1) * 64, wn = (wave >> 1) * 64;
    const int quad = lane >> 4, r = lane & 15;

    f32x4 acc[4][4] = {};

    for (int k0 = 0; k0 < K; k0 += 32) {
        __syncthreads();   // protect LDS from previous iter's readers
        #pragma unroll
        for (int s = t; s < 512; s += 256) {
            int row = s >> 2, part = s & 3;
            uint4 da = *(const uint4*)(A  + (size_t)(bm + row) * K + k0 + part * 8);
            *(uint4*)(&As[row * LDSTRIDE + part * 8]) = da;
            uint4 db = *(const uint4*)(Wt + (size_t)(bn + row) * K + k0 + part * 8);
            *(uint4*)(&Bs[row * LDSTRIDE + part * 8]) = db;
        }
        __syncthreads();

        bf16x8 af[4], bfr[4];
        #pragma unroll
        for (int i = 0; i < 4; i++)
            af[i] = *(const bf16x8*)(&As[(wm + i * 16 + r) * LDSTRIDE + quad * 8]);
        #pragma unroll
        for (int j = 0; j < 4; j++)
            bfr[j] = *(const bf16x8*)(&Bs[(wn + j * 16 + r) * LDSTRIDE + quad * 8]);
        #pragma unroll
        for (int i = 0; i < 4; i++)
            #pragma unroll
            for (int j = 0; j < 4; j++)
                acc[i][j] = __builtin_amdgcn_mfma_f32_16x16x32_bf16(af[i], bfr[j], acc[i][j], 0, 0, 0);
    }

    // epilogue: C/D layout col = lane&15, row = quad*4 + e
    #pragma unroll
    for (int i = 0; i < 4; i++) {
        #pragma unroll
        for (int j = 0; j < 4; j++) {
            int n = bn + wn + j * 16 + r;
            float bv = BIAS ? bias[n] : 0.f;
            #pragma unroll
            for (int e = 0; e < 4; e++) {
                int m = bm + wm + i * 16 + quad * 4 + e;
                float val = acc[i][j][e] + bv;
                if (GELU) val = 0.5f * val * (1.f + erff(val * 0.70710678118654752f));
                if (RESID) val += resid[(size_t)m * N + n];
                if (OUTBF) ((bf16*)outp)[(size_t)m * N + n] = (bf16)val;
                else       ((float*)outp)[(size_t)m * N + n] = val;
            }
        }
    }
}

// ---------------- channel-attn scores: S = softmax(scale * k^T v), per (b,h) ----------
__global__ __launch_bounds__(256)
void attn_scores_kernel(const bf16* __restrict__ qkvb, float* __restrict__ attn) {
    int bh = blockIdx.x;
    int b = bh >> 3, h = bh & 7;
    __shared__ float kl[112][48];
    __shared__ float vl[112][48];
    __shared__ float sl[48][49];
    float acc[9] = {};
    int t = threadIdx.x;
    for (int n0 = 0; n0 < N_; n0 += 112) {
        __syncthreads();
        for (int i = t; i < 112 * 48; i += 256) {
            int nn = i / 48, d = i - nn * 48;
            size_t base = (size_t)(b * N_ + n0 + nn) * 1152;
            kl[nn][d] = (float)qkvb[base + 384 + h * 48 + d];
            vl[nn][d] = (float)qkvb[base + 768 + h * 48 + d];
        }
        __syncthreads();
        #pragma unroll
        for (int rr = 0; rr < 9; rr++) {
            int idx = t + rr * 256;
            int d = idx / 48, e = idx - d * 48;
            float a = acc[rr];
            for (int nn = 0; nn < 112; nn++)
                a += kl[nn][d] * vl[nn][e];
            acc[rr] = a;
        }
    }
    const float scale = 0.14433756729740644f;   // 48^-0.5
    __syncthreads();
    #pragma unroll
    for (int rr = 0; rr < 9; rr++) {
        int idx = t + rr * 256;
        sl[idx / 48][idx % 48] = acc[rr] * scale;
    }
    __syncthreads();
    if (t < 48) {
        float mx = -1e30f;
        for (int e = 0; e < 48; e++) mx = fmaxf(mx, sl[t][e]);
        float s = 0.f;
        for (int e = 0; e < 48; e++) { float ex = __expf(sl[t][e] - mx); sl[t][e] = ex; s += ex; }
        float inv = 1.f / s;
        for (int e = 0; e < 48; e++)
            attn[((size_t)bh * 48 + t) * 48 + e] = sl[t][e] * inv;
    }
}

// ---------------- apply: out[b,n,h*48+d] = sum_e attn[b,h,d,e]*q[b,n,e] -------------
__global__ __launch_bounds__(256)
void attn_apply_kernel(const float* __restrict__ attn, const bf16* __restrict__ qkvb,
                       bf16* __restrict__ outp) {
    int nc = blockIdx.x;   // 7 chunks of 112 rows
    int h = blockIdx.y;
    int b = blockIdx.z;
    __shared__ float al[48][49];
    __shared__ float ql[112][48];
    int t = threadIdx.x;
    for (int i = t; i < 48 * 48; i += 256)
        al[i / 48][i % 48] = attn[(size_t)(b * 8 + h) * 2304 + i];
    int n0 = nc * 112;
    for (int i = t; i < 112 * 48; i += 256) {
        int nn = i / 48, e = i - nn * 48;
        ql[nn][e] = (float)qkvb[(size_t)(b * N_ + n0 + nn) * 1152 + h * 48 + e];
    }
    __syncthreads();
    #pragma unroll
    for (int rr = 0; rr < 21; rr++) {
        int idx = t + rr * 256;
        int nn = idx / 48, d = idx - nn * 48;
        float a = 0.f;
        #pragma unroll
        for (int e = 0; e < 48; e++) a += al[d][e] * ql[nn][e];
        outp[(size_t)(b * N_ + n0 + nn) * C_ + h * 48 + d] = (bf16)a;
    }
}

// ---------------- launch ----------------
extern "C" void kernel_launch(void* const* d_in, const int* in_sizes, int n_in,
                              void* d_out, int out_size, void* d_ws, size_t ws_size,
                              hipStream_t stream) {
    const float* x      = (const float*)d_in[0];
    const float* cpe0_w = (const float*)d_in[3];
    const float* cpe0_b = (const float*)d_in[4];
    const float* cpe1_w = (const float*)d_in[5];
    const float* cpe1_b = (const float*)d_in[6];
    const float* n1g    = (const float*)d_in[7];
    const float* n1b    = (const float*)d_in[8];
    const float* qkv_w  = (const float*)d_in[9];
    const float* proj_w = (const float*)d_in[10];
    const float* proj_b = (const float*)d_in[11];
    const float* n2g    = (const float*)d_in[12];
    const float* n2b    = (const float*)d_in[13];
    const float* fc1_w  = (const float*)d_in[14];
    const float* fc1_b  = (const float*)d_in[15];
    const float* fc2_w  = (const float*)d_in[16];
    const float* fc2_b  = (const float*)d_in[17];

    // workspace layout (bytes)
    char* ws = (char*)d_ws;
    size_t off = 0;
    bf16* cur    = (bf16*)(ws + off); off += (size_t)M_ * C_ * 2;        // LN out / attn_out / LN2 out
    bf16* qkvb   = (bf16*)(ws + off);                                     // qkv bf16; later x3 fp32
    float* x3    = (float*)qkvb;
    off += (size_t)M_ * 1152 * 2;
    float* attn  = (float*)(ws + off); off += (size_t)256 * 48 * 48 * 4;
    bf16* hbuf   = (bf16*)(ws + off); off += (size_t)M_ * HID_ * 2;
    bf16* qkv_wb  = (bf16*)(ws + off); off += (size_t)1152 * 384 * 2;
    bf16* proj_wb = (bf16*)(ws + off); off += (size_t)384 * 384 * 2;
    bf16* fc1_wb  = (bf16*)(ws + off); off += (size_t)HID_ * 384 * 2;
    bf16* fc2_wb  = (bf16*)(ws + off); off += (size_t)384 * HID_ * 2;
    float* out = (float*)d_out;   // doubles as x1/x2 trunk buffer

    // weights -> bf16
    convert_kernel<<<(442368 + 255) / 256, 256, 0, stream>>>(qkv_w, qkv_wb, 442368);
    convert_kernel<<<(147456 + 255) / 256, 256, 0, stream>>>(proj_w, proj_wb, 147456);
    convert_kernel<<<(589824 + 255) / 256, 256, 0, stream>>>(fc1_w, fc1_wb, 589824);
    convert_kernel<<<(589824 + 255) / 256, 256, 0, stream>>>(fc2_w, fc2_wb, 589824);

    // CPE0: x -> out (x1)
    cpe_kernel<<<M_, 384, 0, stream>>>(x, cpe0_w, cpe0_b, out);
    // LN1: out -> cur (bf16)
    ln_kernel<<<M_ / 4, 256, 0, stream>>>(out, n1g, n1b, cur);
    // qkv: cur @ qkv_w^T -> qkvb  (M x 1152, K=384)
    gemm_kernel<false, false, false, true><<<dim3(1152 / 128, M_ / 128), 256, 0, stream>>>(
        cur, qkv_wb, nullptr, nullptr, qkvb, M_, 1152, 384);
    // channel attention
    attn_scores_kernel<<<256, 256, 0, stream>>>(qkvb, attn);
    attn_apply_kernel<<<dim3(7, 8, 32), 256, 0, stream>>>(attn, qkvb, cur);
    // proj + bias + residual: out = out + attn_out @ proj_w^T + b   (fp32 out)
    gemm_kernel<true, false, true, false><<<dim3(384 / 128, M_ / 128), 256, 0, stream>>>(
        cur, proj_wb, proj_b, out, out, M_, 384, 384);
    // CPE1: out (x2) -> x3
    cpe_kernel<<<M_, 384, 0, stream>>>(out, cpe1_w, cpe1_b, x3);
    // LN2: x3 -> cur
    ln_kernel<<<M_ / 4, 256, 0, stream>>>(x3, n2g, n2b, cur);
    // fc1 + bias + gelu -> hbuf (bf16), M x 1536, K=384
    gemm_kernel<true, true, false, true><<<dim3(HID_ / 128, M_ / 128), 256, 0, stream>>>(
        cur, fc1_wb, fc1_b, nullptr, hbuf, M_, HID_, 384);
    // fc2 + bias + residual x3 -> d_out (fp32), M x 384, K=1536
    gemm_kernel<true, false, true, false><<<dim3(384 / 128, M_ / 128), 256, 0, stream>>>(
        hbuf, fc2_wb, fc2_b, x3, out, M_, 384, HID_);
}

// Round 2
// 585.193 us; speedup vs baseline: 1.2859x; 1.2859x over previous
//
#include <hip/hip_runtime.h>
#include <hip/hip_bf16.h>
#include <math.h>

#define B_     32
#define HH_    28
#define WW_    28
#define N_     784
#define C_     384
#define M_     25088      // B_*N_
#define HEADS_ 8
#define HD_    48
#define HID_   1536

typedef __bf16 bf16;
typedef __attribute__((ext_vector_type(8))) __bf16 bf16x8;
typedef __attribute__((ext_vector_type(4))) __bf16 bf16x4;
typedef __attribute__((ext_vector_type(4))) float f32x4;

// ---------------- weight fp32 -> bf16 ----------------
__global__ void convert_kernel(const float* __restrict__ in, bf16* __restrict__ out, int n) {
    int i = blockIdx.x * 256 + threadIdx.x;
    if (i < n) out[i] = (bf16)in[i];
}

// ---------------- depthwise 3x3 conv + bias + residual (CPE) ----------------
__global__ __launch_bounds__(384)
void cpe_kernel(const float* __restrict__ x, const float* __restrict__ w,
                const float* __restrict__ bias, float* __restrict__ y) {
    int row = blockIdx.x;          // b*784 + n
    int c = threadIdx.x;
    int b = row / N_;
    int n = row - b * N_;
    int py = n / WW_, px = n - py * WW_;
    float acc = bias[c];
    #pragma unroll
    for (int ky = 0; ky < 3; ky++) {
        int yy = py + ky - 1;
        if (yy < 0 || yy >= HH_) continue;
        #pragma unroll
        for (int kx = 0; kx < 3; kx++) {
            int xx = px + kx - 1;
            if (xx < 0 || xx >= WW_) continue;
            acc += w[c * 9 + ky * 3 + kx] * x[(size_t)(b * N_ + yy * WW_ + xx) * C_ + c];
        }
    }
    y[(size_t)row * C_ + c] = x[(size_t)row * C_ + c] + acc;
}

// ---------------- layernorm fp32 -> bf16, one wave per row ----------------
__global__ __launch_bounds__(256)
void ln_kernel(const float* __restrict__ x, const float* __restrict__ g,
               const float* __restrict__ beta, bf16* __restrict__ out) {
    int wave = threadIdx.x >> 6;
    int lane = threadIdx.x & 63;
    int row = blockIdx.x * 4 + wave;
    const float* xr = x + (size_t)row * C_;
    float v[6];
    float s = 0.f;
    #pragma unroll
    for (int i = 0; i < 6; i++) { v[i] = xr[lane + i * 64]; s += v[i]; }
    #pragma unroll
    for (int off = 32; off; off >>= 1) s += __shfl_down(s, off, 64);
    s = __shfl(s, 0, 64);
    float mean = s * (1.f / C_);
    float var = 0.f;
    #pragma unroll
    for (int i = 0; i < 6; i++) { float d = v[i] - mean; var += d * d; }
    #pragma unroll
    for (int off = 32; off; off >>= 1) var += __shfl_down(var, off, 64);
    var = __shfl(var, 0, 64);
    float rstd = rsqrtf(var * (1.f / C_) + 1e-5f);
    bf16* orow = out + (size_t)row * C_;
    #pragma unroll
    for (int i = 0; i < 6; i++) {
        int c = lane + i * 64;
        orow[c] = (bf16)((v[i] - mean) * rstd * g[c] + beta[c]);
    }
}

// ---------------- bf16 MFMA GEMM (as R1; proven correct) ----------------
#define LDSTRIDE 40   // 32 + 8 pad: 80B rows -> 2-way bank aliasing (free)
template<bool BIAS, bool GELU, bool RESID, bool OUTBF>
__global__ __launch_bounds__(256)
void gemm_kernel(const bf16* __restrict__ A, const bf16* __restrict__ Wt,
                 const float* __restrict__ bias, const float* __restrict__ resid,
                 void* __restrict__ outp, int M, int N, int K) {
    __shared__ __align__(16) bf16 As[128 * LDSTRIDE];
    __shared__ __align__(16) bf16 Bs[128 * LDSTRIDE];
    const int bm = blockIdx.y * 128, bn = blockIdx.x * 128;
    const int t = threadIdx.x;
    const int wave = t >> 6, lane = t & 63;
    const int wm = (wave & 1) * 64, wn = (wave >> 1) * 64;
    const int quad = lane >> 4, r = lane & 15;

    f32x4 acc[4][4] = {};

    for (int k0 = 0; k0 < K; k0 += 32) {
        __syncthreads();
        #pragma unroll
        for (int s = t; s < 512; s += 256) {
            int row = s >> 2, part = s & 3;
            uint4 da = *(const uint4*)(A  + (size_t)(bm + row) * K + k0 + part * 8);
            *(uint4*)(&As[row * LDSTRIDE + part * 8]) = da;
            uint4 db = *(const uint4*)(Wt + (size_t)(bn + row) * K + k0 + part * 8);
            *(uint4*)(&Bs[row * LDSTRIDE + part * 8]) = db;
        }
        __syncthreads();

        bf16x8 af[4], bfr[4];
        #pragma unroll
        for (int i = 0; i < 4; i++)
            af[i] = *(const bf16x8*)(&As[(wm + i * 16 + r) * LDSTRIDE + quad * 8]);
        #pragma unroll
        for (int j = 0; j < 4; j++)
            bfr[j] = *(const bf16x8*)(&Bs[(wn + j * 16 + r) * LDSTRIDE + quad * 8]);
        #pragma unroll
        for (int i = 0; i < 4; i++)
            #pragma unroll
            for (int j = 0; j < 4; j++)
                acc[i][j] = __builtin_amdgcn_mfma_f32_16x16x32_bf16(af[i], bfr[j], acc[i][j], 0, 0, 0);
    }

    #pragma unroll
    for (int i = 0; i < 4; i++) {
        #pragma unroll
        for (int j = 0; j < 4; j++) {
            int n = bn + wn + j * 16 + r;
            float bv = BIAS ? bias[n] : 0.f;
            #pragma unroll
            for (int e = 0; e < 4; e++) {
                int m = bm + wm + i * 16 + quad * 4 + e;
                float val = acc[i][j][e] + bv;
                if (GELU) val = 0.5f * val * (1.f + erff(val * 0.70710678118654752f));
                if (RESID) val += resid[(size_t)m * N + n];
                if (OUTBF) ((bf16*)outp)[(size_t)m * N + n] = (bf16)val;
                else       ((float*)outp)[(size_t)m * N + n] = val;
            }
        }
    }
}

// ---------------- fused channel attention (scores + softmax + apply), MFMA ----------
// One block per (b,h). Phase 1: S = k^T v via 16x16x32 MFMA, per-wave n-chunks of 32
// staged transposed in per-wave LDS (stride 40 = 2-way-free banks). Phase 2: softmax
// rows, attn stored bf16 zero-padded to e=64 so phase 3 needs no k-masking.
// Phase 3: out = attn @ q^T; B-fragments read straight from global (q rows are
// already B^T fragment layout).
__global__ __launch_bounds__(256)
void attn_fused_kernel(const bf16* __restrict__ qkvb, bf16* __restrict__ outp) {
    __shared__ __align__(16) bf16 stage[4][3872];   // per wave: kT[48*40] | pad16 | vT[48*40]
    __shared__ float Sred[4][48][49];
    __shared__ __align__(16) bf16 attn_s[48 * 72];  // stride 72: 2-way-free b128 reads

    const int bh = blockIdx.x;
    const int b = bh >> 3, h = bh & 7;
    const int t = threadIdx.x;
    const int wave = t >> 6, lane = t & 63;
    const int quad = lane >> 4, r = lane & 15;
    const int tensor = lane >> 5;            // 0 = k, 1 = v
    const int n_local = lane & 31;

    const size_t qkv_base = (size_t)b * N_ * 1152;
    const int toff = 384 + tensor * 384 + h * 48;   // k at 384+, v at 768+

    f32x4 acc[3][3] = {};
    bf16* kT = &stage[wave][0];
    bf16* vT = &stage[wave][1936];
    bf16* myT = &stage[wave][tensor * 1936];

    // ---- phase 1: scores ----
    for (int c = wave; c < 25; c += 4) {
        int n0 = c * 32;
        bf16 rowbuf[48];
        if (n0 + n_local < N_) {
            const uint4* src = (const uint4*)(qkvb + qkv_base + (size_t)(n0 + n_local) * 1152 + toff);
            #pragma unroll
            for (int i = 0; i < 6; i++) *(uint4*)(&rowbuf[i * 8]) = src[i];
        } else {
            #pragma unroll
            for (int i = 0; i < 48; i++) rowbuf[i] = (bf16)0.f;
        }
        #pragma unroll
        for (int d = 0; d < 48; d++) myT[d * 40 + n_local] = rowbuf[d];
        // wave-synchronous LDS: same wave writes then reads; lgkmcnt ordering suffices
        bf16x8 af[3], bfv[3];
        #pragma unroll
        for (int i = 0; i < 3; i++) af[i]  = *(const bf16x8*)(&kT[(i * 16 + r) * 40 + quad * 8]);
        #pragma unroll
        for (int j = 0; j < 3; j++) bfv[j] = *(const bf16x8*)(&vT[(j * 16 + r) * 40 + quad * 8]);
        #pragma unroll
        for (int i = 0; i < 3; i++)
            #pragma unroll
            for (int j = 0; j < 3; j++)
                acc[i][j] = __builtin_amdgcn_mfma_f32_16x16x32_bf16(af[i], bfv[j], acc[i][j], 0, 0, 0);
    }

    // partial S -> LDS (C/D layout: row = quad*4+e, col = r)
    #pragma unroll
    for (int i = 0; i < 3; i++)
        #pragma unroll
        for (int j = 0; j < 3; j++)
            #pragma unroll
            for (int e = 0; e < 4; e++)
                Sred[wave][i * 16 + quad * 4 + e][j * 16 + r] = acc[i][j][e];
    __syncthreads();

    // ---- phase 2: softmax over e for each d-row ----
    if (t < 48) {
        float row[48];
        float mx = -1e30f;
        #pragma unroll
        for (int e = 0; e < 48; e++) {
            float s = Sred[0][t][e] + Sred[1][t][e] + Sred[2][t][e] + Sred[3][t][e];
            s *= 0.14433756729740644f;   // 48^-0.5
            row[e] = s;
            mx = fmaxf(mx, s);
        }
        float sum = 0.f;
        #pragma unroll
        for (int e = 0; e < 48; e++) { float ex = __expf(row[e] - mx); row[e] = ex; sum += ex; }
        float inv = 1.f / sum;
        #pragma unroll
        for (int e = 0; e < 48; e++) attn_s[t * 72 + e] = (bf16)(row[e] * inv);
        #pragma unroll
        for (int e = 48; e < 64; e++) attn_s[t * 72 + e] = (bf16)0.f;
    }
    __syncthreads();

    // ---- phase 3: out[n, h*48+d] = sum_e attn[d,e] q[n,e] ----
    const bf16* qbase = qkvb + qkv_base + h * 48;
    for (int nt = wave; nt < 49; nt += 4) {
        int n0 = nt * 16;
        f32x4 oacc[3] = {};
        #pragma unroll
        for (int kc = 0; kc < 2; kc++) {
            // B^T[col=token][e-slice]; for kc=1 quads 2,3 read into k-region — harmless,
            // attn_s is zero there.
            bf16x8 bq = *(const bf16x8*)(qbase + (size_t)(n0 + r) * 1152 + kc * 32 + quad * 8);
            #pragma unroll
            for (int i = 0; i < 3; i++) {
                bf16x8 aa = *(const bf16x8*)(&attn_s[(i * 16 + r) * 72 + kc * 32 + quad * 8]);
                oacc[i] = __builtin_amdgcn_mfma_f32_16x16x32_bf16(aa, bq, oacc[i], 0, 0, 0);
            }
        }
        #pragma unroll
        for (int i = 0; i < 3; i++) {
            bf16x4 ov;
            #pragma unroll
            for (int e = 0; e < 4; e++) ov[e] = (bf16)oacc[i][e];
            *(bf16x4*)(outp + (size_t)(b * N_ + n0 + r) * 384 + h * 48 + i * 16 + quad * 4) = ov;
        }
    }
}

// ---------------- launch ----------------
extern "C" void kernel_launch(void* const* d_in, const int* in_sizes, int n_in,
                              void* d_out, int out_size, void* d_ws, size_t ws_size,
                              hipStream_t stream) {
    const float* x      = (const float*)d_in[0];
    const float* cpe0_w = (const float*)d_in[3];
    const float* cpe0_b = (const float*)d_in[4];
    const float* cpe1_w = (const float*)d_in[5];
    const float* cpe1_b = (const float*)d_in[6];
    const float* n1g    = (const float*)d_in[7];
    const float* n1b    = (const float*)d_in[8];
    const float* qkv_w  = (const float*)d_in[9];
    const float* proj_w = (const float*)d_in[10];
    const float* proj_b = (const float*)d_in[11];
    const float* n2g    = (const float*)d_in[12];
    const float* n2b    = (const float*)d_in[13];
    const float* fc1_w  = (const float*)d_in[14];
    const float* fc1_b  = (const float*)d_in[15];
    const float* fc2_w  = (const float*)d_in[16];
    const float* fc2_b  = (const float*)d_in[17];

    // workspace layout (bytes)
    char* ws = (char*)d_ws;
    size_t off = 0;
    bf16* cur    = (bf16*)(ws + off); off += (size_t)M_ * C_ * 2;        // LN out / attn_out / LN2 out
    bf16* qkvb   = (bf16*)(ws + off);                                     // qkv bf16; later x3 fp32
    float* x3    = (float*)qkvb;
    off += (size_t)M_ * 1152 * 2;
    bf16* hbuf   = (bf16*)(ws + off); off += (size_t)M_ * HID_ * 2;
    bf16* qkv_wb  = (bf16*)(ws + off); off += (size_t)1152 * 384 * 2;
    bf16* proj_wb = (bf16*)(ws + off); off += (size_t)384 * 384 * 2;
    bf16* fc1_wb  = (bf16*)(ws + off); off += (size_t)HID_ * 384 * 2;
    bf16* fc2_wb  = (bf16*)(ws + off); off += (size_t)384 * HID_ * 2;
    float* out = (float*)d_out;   // doubles as x1/x2 trunk buffer

    // weights -> bf16
    convert_kernel<<<(442368 + 255) / 256, 256, 0, stream>>>(qkv_w, qkv_wb, 442368);
    convert_kernel<<<(147456 + 255) / 256, 256, 0, stream>>>(proj_w, proj_wb, 147456);
    convert_kernel<<<(589824 + 255) / 256, 256, 0, stream>>>(fc1_w, fc1_wb, 589824);
    convert_kernel<<<(589824 + 255) / 256, 256, 0, stream>>>(fc2_w, fc2_wb, 589824);

    // CPE0: x -> out (x1)
    cpe_kernel<<<M_, 384, 0, stream>>>(x, cpe0_w, cpe0_b, out);
    // LN1: out -> cur (bf16)
    ln_kernel<<<M_ / 4, 256, 0, stream>>>(out, n1g, n1b, cur);
    // qkv: cur @ qkv_w^T -> qkvb  (M x 1152, K=384)
    gemm_kernel<false, false, false, true><<<dim3(1152 / 128, M_ / 128), 256, 0, stream>>>(
        cur, qkv_wb, nullptr, nullptr, qkvb, M_, 1152, 384);
    // fused channel attention -> cur (bf16 attn_out)
    attn_fused_kernel<<<256, 256, 0, stream>>>(qkvb, cur);
    // proj + bias + residual: out = out + attn_out @ proj_w^T + b   (fp32 out)
    gemm_kernel<true, false, true, false><<<dim3(384 / 128, M_ / 128), 256, 0, stream>>>(
        cur, proj_wb, proj_b, out, out, M_, 384, 384);
    // CPE1: out (x2) -> x3
    cpe_kernel<<<M_, 384, 0, stream>>>(out, cpe1_w, cpe1_b, x3);
    // LN2: x3 -> cur
    ln_kernel<<<M_ / 4, 256, 0, stream>>>(x3, n2g, n2b, cur);
    // fc1 + bias + gelu -> hbuf (bf16), M x 1536, K=384
    gemm_kernel<true, true, false, true><<<dim3(HID_ / 128, M_ / 128), 256, 0, stream>>>(
        cur, fc1_wb, fc1_b, nullptr, hbuf, M_, HID_, 384);
    // fc2 + bias + residual x3 -> d_out (fp32), M x 384, K=1536
    gemm_kernel<true, false, true, false><<<dim3(384 / 128, M_ / 128), 256, 0, stream>>>(
        hbuf, fc2_wb, fc2_b, x3, out, M_, 384, HID_);
}

// Round 3
// 555.515 us; speedup vs baseline: 1.3546x; 1.0534x over previous
//
#include <hip/hip_runtime.h>
#include <hip/hip_bf16.h>
#include <math.h>
#include <stdint.h>

#define B_     32
#define HH_    28
#define WW_    28
#define N_     784
#define C_     384
#define M_     25088      // B_*N_
#define HEADS_ 8
#define HD_    48
#define HID_   1536

typedef __bf16 bf16;
typedef __attribute__((ext_vector_type(8))) __bf16 bf16x8;
typedef __attribute__((ext_vector_type(4))) __bf16 bf16x4;
typedef __attribute__((ext_vector_type(4))) float f32x4;

// async global->LDS, 16B per lane; LDS dest = wave-uniform base + lane*16
__device__ __forceinline__ void gload_lds16(const void* g, void* l) {
    __builtin_amdgcn_global_load_lds(
        (const __attribute__((address_space(1))) unsigned int*)g,
        (__attribute__((address_space(3))) unsigned int*)(uintptr_t)l,
        16, 0, 0);
}

// ---------------- weights fp32 -> bf16, all four in one launch ----------------
__global__ void convert4_kernel(const float* __restrict__ a, int na,
                                const float* __restrict__ b, int nb,
                                const float* __restrict__ c, int nc,
                                const float* __restrict__ d, int nd,
                                bf16* __restrict__ out) {
    int i = blockIdx.x * 256 + threadIdx.x;
    int j = i;
    const float* src;
    if (j < na) src = a + j;
    else { j -= na;
        if (j < nb) src = b + j;
        else { j -= nb;
            if (j < nc) src = c + j;
            else { j -= nc;
                if (j >= nd) return;
                src = d + j; } } }
    out[i] = (bf16)(*src);
}

// ---------------- depthwise 3x3 conv + bias + residual (CPE), float4 ----------------
// block = 384 threads = 4 positions x 96 channel-quads; grid = M_/4
__global__ __launch_bounds__(384)
void cpe_kernel(const float* __restrict__ x, const float* __restrict__ w,
                const float* __restrict__ bias, float* __restrict__ y) {
    int t = threadIdx.x;
    int tpos = t / 96;
    int c4 = (t - tpos * 96) * 4;
    int row = blockIdx.x * 4 + tpos;     // b*784 + n ; 4 | 28 so no row straddle
    int b = row / N_;
    int n = row - b * N_;
    int py = n / WW_, px = n - py * WW_;
    const float* wc = w + c4 * 9;
    float4 acc = *(const float4*)(bias + c4);
    float4 ctr = *(const float4*)(x + (size_t)row * C_ + c4);
    #pragma unroll
    for (int ky = 0; ky < 3; ky++) {
        int yy = py + ky - 1;
        if (yy < 0 || yy >= HH_) continue;
        #pragma unroll
        for (int kx = 0; kx < 3; kx++) {
            int xx = px + kx - 1;
            if (xx < 0 || xx >= WW_) continue;
            int tap = ky * 3 + kx;
            float4 xv = (ky == 1 && kx == 1) ? ctr
                      : *(const float4*)(x + (size_t)(b * N_ + yy * WW_ + xx) * C_ + c4);
            acc.x += wc[tap] * xv.x;
            acc.y += wc[9 + tap] * xv.y;
            acc.z += wc[18 + tap] * xv.z;
            acc.w += wc[27 + tap] * xv.w;
        }
    }
    acc.x += ctr.x; acc.y += ctr.y; acc.z += ctr.z; acc.w += ctr.w;
    *(float4*)(y + (size_t)row * C_ + c4) = acc;
}

// ---------------- layernorm fp32 -> bf16, one wave per row ----------------
__global__ __launch_bounds__(256)
void ln_kernel(const float* __restrict__ x, const float* __restrict__ g,
               const float* __restrict__ beta, bf16* __restrict__ out) {
    int wave = threadIdx.x >> 6;
    int lane = threadIdx.x & 63;
    int row = blockIdx.x * 4 + wave;
    const float* xr = x + (size_t)row * C_;
    float v[6];
    float s = 0.f;
    #pragma unroll
    for (int i = 0; i < 6; i++) { v[i] = xr[lane + i * 64]; s += v[i]; }
    #pragma unroll
    for (int off = 32; off; off >>= 1) s += __shfl_down(s, off, 64);
    s = __shfl(s, 0, 64);
    float mean = s * (1.f / C_);
    float var = 0.f;
    #pragma unroll
    for (int i = 0; i < 6; i++) { float d = v[i] - mean; var += d * d; }
    #pragma unroll
    for (int off = 32; off; off >>= 1) var += __shfl_down(var, off, 64);
    var = __shfl(var, 0, 64);
    float rstd = rsqrtf(var * (1.f / C_) + 1e-5f);
    bf16* orow = out + (size_t)row * C_;
    #pragma unroll
    for (int i = 0; i < 6; i++) {
        int c = lane + i * 64;
        orow[c] = (bf16)((v[i] - mean) * rstd * g[c] + beta[c]);
    }
}

// ---------------- bf16 MFMA GEMM with global_load_lds staging (m97 structure) -------
// A: M x K bf16 row-major, W: N x K bf16 row-major. 128x128 tile, BK=32, 256 thr.
// LDS tiles UNPADDED stride 32 (required: global_load_lds lands lane i at base+16*i).
template<bool BIAS, bool GELU, bool RESID, bool OUTBF>
__global__ __launch_bounds__(256)
void gemm_kernel(const bf16* __restrict__ A, const bf16* __restrict__ Wt,
                 const float* __restrict__ bias, const float* __restrict__ resid,
                 void* __restrict__ outp, int M, int N, int K) {
    __shared__ __align__(16) bf16 As[128 * 32];
    __shared__ __align__(16) bf16 Bs[128 * 32];
    const int bm = blockIdx.y * 128, bn = blockIdx.x * 128;
    const int t = threadIdx.x;
    const int wave = t >> 6, lane = t & 63;
    const int wm = (wave & 1) * 64, wn = (wave >> 1) * 64;
    const int quad = lane >> 4, r = lane & 15;

    // staging addresses: wave w, issue j covers tile rows [w*32+j*16, +16)
    const int ldrow = lane >> 2;            // 0..15
    const int ldcol = (lane & 3) * 8;       // bf16 elements
    const bf16* ga0 = A  + (size_t)(bm + wave * 32 + ldrow) * K + ldcol;
    const bf16* ga1 = ga0 + (size_t)16 * K;
    const bf16* gb0 = Wt + (size_t)(bn + wave * 32 + ldrow) * K + ldcol;
    const bf16* gb1 = gb0 + (size_t)16 * K;
    bf16* la0 = &As[(wave * 32) * 32];
    bf16* la1 = &As[(wave * 32 + 16) * 32];
    bf16* lb0 = &Bs[(wave * 32) * 32];
    bf16* lb1 = &Bs[(wave * 32 + 16) * 32];

    f32x4 acc[4][4] = {};

    for (int k0 = 0; k0 < K; k0 += 32) {
        __syncthreads();                    // WAR: prior readers done
        gload_lds16(ga0 + k0, la0);
        gload_lds16(ga1 + k0, la1);
        gload_lds16(gb0 + k0, lb0);
        gload_lds16(gb1 + k0, lb1);
        __syncthreads();                    // RAW: vmcnt drained by barrier semantics

        bf16x8 af[4], bfr[4];
        #pragma unroll
        for (int i = 0; i < 4; i++)
            af[i] = *(const bf16x8*)(&As[(wm + i * 16 + r) * 32 + quad * 8]);
        #pragma unroll
        for (int j = 0; j < 4; j++)
            bfr[j] = *(const bf16x8*)(&Bs[(wn + j * 16 + r) * 32 + quad * 8]);
        #pragma unroll
        for (int i = 0; i < 4; i++)
            #pragma unroll
            for (int j = 0; j < 4; j++)
                acc[i][j] = __builtin_amdgcn_mfma_f32_16x16x32_bf16(af[i], bfr[j], acc[i][j], 0, 0, 0);
    }

    // epilogue: C/D layout col = lane&15, row = quad*4 + e
    #pragma unroll
    for (int i = 0; i < 4; i++) {
        #pragma unroll
        for (int j = 0; j < 4; j++) {
            int n = bn + wn + j * 16 + r;
            float bv = BIAS ? bias[n] : 0.f;
            #pragma unroll
            for (int e = 0; e < 4; e++) {
                int m = bm + wm + i * 16 + quad * 4 + e;
                float val = acc[i][j][e] + bv;
                if (GELU) val = 0.5f * val * (1.f + erff(val * 0.70710678118654752f));
                if (RESID) val += resid[(size_t)m * N + n];
                if (OUTBF) ((bf16*)outp)[(size_t)m * N + n] = (bf16)val;
                else       ((float*)outp)[(size_t)m * N + n] = val;
            }
        }
    }
}

// ---------------- fused channel attention (scores + softmax + apply), MFMA ----------
__global__ __launch_bounds__(256)
void attn_fused_kernel(const bf16* __restrict__ qkvb, bf16* __restrict__ outp) {
    __shared__ __align__(16) bf16 stage[4][3872];   // per wave: kT[48*40] | pad | vT[48*40]
    __shared__ float Sred[4][48][49];
    __shared__ __align__(16) bf16 attn_s[48 * 72];  // stride 72: 2-way-free b128 reads

    const int bh = blockIdx.x;
    const int b = bh >> 3, h = bh & 7;
    const int t = threadIdx.x;
    const int wave = t >> 6, lane = t & 63;
    const int quad = lane >> 4, r = lane & 15;
    const int tensor = lane >> 5;            // 0 = k, 1 = v
    const int n_local = lane & 31;

    const size_t qkv_base = (size_t)b * N_ * 1152;
    const int toff = 384 + tensor * 384 + h * 48;

    f32x4 acc[3][3] = {};
    bf16* kT = &stage[wave][0];
    bf16* vT = &stage[wave][1936];
    bf16* myT = &stage[wave][tensor * 1936];

    // ---- phase 1: scores S = k^T v ----
    for (int c = wave; c < 25; c += 4) {
        int n0 = c * 32;
        bf16 rowbuf[48];
        if (n0 + n_local < N_) {
            const uint4* src = (const uint4*)(qkvb + qkv_base + (size_t)(n0 + n_local) * 1152 + toff);
            #pragma unroll
            for (int i = 0; i < 6; i++) *(uint4*)(&rowbuf[i * 8]) = src[i];
        } else {
            #pragma unroll
            for (int i = 0; i < 48; i++) rowbuf[i] = (bf16)0.f;
        }
        #pragma unroll
        for (int d = 0; d < 48; d++) myT[d * 40 + n_local] = rowbuf[d];
        bf16x8 af[3], bfv[3];
        #pragma unroll
        for (int i = 0; i < 3; i++) af[i]  = *(const bf16x8*)(&kT[(i * 16 + r) * 40 + quad * 8]);
        #pragma unroll
        for (int j = 0; j < 3; j++) bfv[j] = *(const bf16x8*)(&vT[(j * 16 + r) * 40 + quad * 8]);
        #pragma unroll
        for (int i = 0; i < 3; i++)
            #pragma unroll
            for (int j = 0; j < 3; j++)
                acc[i][j] = __builtin_amdgcn_mfma_f32_16x16x32_bf16(af[i], bfv[j], acc[i][j], 0, 0, 0);
    }

    #pragma unroll
    for (int i = 0; i < 3; i++)
        #pragma unroll
        for (int j = 0; j < 3; j++)
            #pragma unroll
            for (int e = 0; e < 4; e++)
                Sred[wave][i * 16 + quad * 4 + e][j * 16 + r] = acc[i][j][e];
    __syncthreads();

    // ---- phase 2: softmax per d-row ----
    if (t < 48) {
        float row[48];
        float mx = -1e30f;
        #pragma unroll
        for (int e = 0; e < 48; e++) {
            float s = Sred[0][t][e] + Sred[1][t][e] + Sred[2][t][e] + Sred[3][t][e];
            s *= 0.14433756729740644f;   // 48^-0.5
            row[e] = s;
            mx = fmaxf(mx, s);
        }
        float sum = 0.f;
        #pragma unroll
        for (int e = 0; e < 48; e++) { float ex = __expf(row[e] - mx); row[e] = ex; sum += ex; }
        float inv = 1.f / sum;
        #pragma unroll
        for (int e = 0; e < 48; e++) attn_s[t * 72 + e] = (bf16)(row[e] * inv);
        #pragma unroll
        for (int e = 48; e < 64; e++) attn_s[t * 72 + e] = (bf16)0.f;
    }
    __syncthreads();

    // ---- phase 3: out = attn @ q^T ----
    const bf16* qbase = qkvb + qkv_base + h * 48;
    for (int nt = wave; nt < 49; nt += 4) {
        int n0 = nt * 16;
        f32x4 oacc[3] = {};
        #pragma unroll
        for (int kc = 0; kc < 2; kc++) {
            bf16x8 bq = *(const bf16x8*)(qbase + (size_t)(n0 + r) * 1152 + kc * 32 + quad * 8);
            #pragma unroll
            for (int i = 0; i < 3; i++) {
                bf16x8 aa = *(const bf16x8*)(&attn_s[(i * 16 + r) * 72 + kc * 32 + quad * 8]);
                oacc[i] = __builtin_amdgcn_mfma_f32_16x16x32_bf16(aa, bq, oacc[i], 0, 0, 0);
            }
        }
        #pragma unroll
        for (int i = 0; i < 3; i++) {
            bf16x4 ov;
            #pragma unroll
            for (int e = 0; e < 4; e++) ov[e] = (bf16)oacc[i][e];
            *(bf16x4*)(outp + (size_t)(b * N_ + n0 + r) * 384 + h * 48 + i * 16 + quad * 4) = ov;
        }
    }
}

// ---------------- launch ----------------
extern "C" void kernel_launch(void* const* d_in, const int* in_sizes, int n_in,
                              void* d_out, int out_size, void* d_ws, size_t ws_size,
                              hipStream_t stream) {
    const float* x      = (const float*)d_in[0];
    const float* cpe0_w = (const float*)d_in[3];
    const float* cpe0_b = (const float*)d_in[4];
    const float* cpe1_w = (const float*)d_in[5];
    const float* cpe1_b = (const float*)d_in[6];
    const float* n1g    = (const float*)d_in[7];
    const float* n1b    = (const float*)d_in[8];
    const float* qkv_w  = (const float*)d_in[9];
    const float* proj_w = (const float*)d_in[10];
    const float* proj_b = (const float*)d_in[11];
    const float* n2g    = (const float*)d_in[12];
    const float* n2b    = (const float*)d_in[13];
    const float* fc1_w  = (const float*)d_in[14];
    const float* fc1_b  = (const float*)d_in[15];
    const float* fc2_w  = (const float*)d_in[16];
    const float* fc2_b  = (const float*)d_in[17];

    // workspace layout (bytes)
    char* ws = (char*)d_ws;
    size_t off = 0;
    bf16* cur    = (bf16*)(ws + off); off += (size_t)M_ * C_ * 2;
    bf16* qkvb   = (bf16*)(ws + off);
    float* x3    = (float*)qkvb;
    off += (size_t)M_ * 1152 * 2;
    bf16* hbuf   = (bf16*)(ws + off); off += (size_t)M_ * HID_ * 2;
    bf16* qkv_wb  = (bf16*)(ws + off); off += (size_t)1152 * 384 * 2;
    bf16* proj_wb = (bf16*)(ws + off); off += (size_t)384 * 384 * 2;
    bf16* fc1_wb  = (bf16*)(ws + off); off += (size_t)HID_ * 384 * 2;
    bf16* fc2_wb  = (bf16*)(ws + off); off += (size_t)384 * HID_ * 2;
    float* out = (float*)d_out;   // doubles as x1/x2 trunk buffer

    // weights -> bf16 (contiguous outputs: qkv|proj|fc1|fc2), one launch
    const int na = 442368, nb = 147456, nc = 589824, nd = 589824;
    convert4_kernel<<<(na + nb + nc + nd + 255) / 256, 256, 0, stream>>>(
        qkv_w, na, proj_w, nb, fc1_w, nc, fc2_w, nd, qkv_wb);

    // CPE0: x -> out (x1)
    cpe_kernel<<<M_ / 4, 384, 0, stream>>>(x, cpe0_w, cpe0_b, out);
    // LN1: out -> cur (bf16)
    ln_kernel<<<M_ / 4, 256, 0, stream>>>(out, n1g, n1b, cur);
    // qkv: cur @ qkv_w^T -> qkvb  (M x 1152, K=384)
    gemm_kernel<false, false, false, true><<<dim3(1152 / 128, M_ / 128), 256, 0, stream>>>(
        cur, qkv_wb, nullptr, nullptr, qkvb, M_, 1152, 384);
    // fused channel attention -> cur
    attn_fused_kernel<<<256, 256, 0, stream>>>(qkvb, cur);
    // proj + bias + residual -> out (fp32)
    gemm_kernel<true, false, true, false><<<dim3(384 / 128, M_ / 128), 256, 0, stream>>>(
        cur, proj_wb, proj_b, out, out, M_, 384, 384);
    // CPE1: out (x2) -> x3
    cpe_kernel<<<M_ / 4, 384, 0, stream>>>(out, cpe1_w, cpe1_b, x3);
    // LN2: x3 -> cur
    ln_kernel<<<M_ / 4, 256, 0, stream>>>(x3, n2g, n2b, cur);
    // fc1 + bias + gelu -> hbuf (bf16), M x 1536, K=384
    gemm_kernel<true, true, false, true><<<dim3(HID_ / 128, M_ / 128), 256, 0, stream>>>(
        cur, fc1_wb, fc1_b, nullptr, hbuf, M_, HID_, 384);
    // fc2 + bias + residual x3 -> d_out (fp32), M x 384, K=1536
    gemm_kernel<true, false, true, false><<<dim3(384 / 128, M_ / 128), 256, 0, stream>>>(
        hbuf, fc2_wb, fc2_b, x3, out, M_, 384, HID_);
}

// Round 5
// 479.180 us; speedup vs baseline: 1.5704x; 1.1593x over previous
//
#include <hip/hip_runtime.h>
#include <hip/hip_bf16.h>
#include <math.h>
#include <stdint.h>

#define B_     32
#define HH_    28
#define WW_    28
#define N_     784
#define C_     384
#define M_     25088      // B_*N_
#define HEADS_ 8
#define HD_    48
#define HID_   1536

typedef __bf16 bf16;
typedef __attribute__((ext_vector_type(8))) __bf16 bf16x8;
typedef __attribute__((ext_vector_type(4))) __bf16 bf16x4;
typedef __attribute__((ext_vector_type(4))) float f32x4;

// async global->LDS, 16B per lane; LDS dest = wave-uniform base + lane*16
__device__ __forceinline__ void gload_lds16(const void* g, void* l) {
    __builtin_amdgcn_global_load_lds(
        (const __attribute__((address_space(1))) unsigned int*)g,
        (__attribute__((address_space(3))) unsigned int*)(uintptr_t)l,
        16, 0, 0);
}

// ---------------- weights fp32 -> bf16, all four in one launch ----------------
__global__ void convert4_kernel(const float* __restrict__ a, int na,
                                const float* __restrict__ b, int nb,
                                const float* __restrict__ c, int nc,
                                const float* __restrict__ d, int nd,
                                bf16* __restrict__ out) {
    int i = blockIdx.x * 256 + threadIdx.x;
    int j = i;
    const float* src;
    if (j < na) src = a + j;
    else { j -= na;
        if (j < nb) src = b + j;
        else { j -= nb;
            if (j < nc) src = c + j;
            else { j -= nc;
                if (j >= nd) return;
                src = d + j; } } }
    out[i] = (bf16)(*src);
}

// ------- depthwise 3x3 conv + bias + residual, fused LayerNorm -> bf16 -------
// block = 384 threads = 4 rows x 96 channel-quads; grid = M_/4 (4 | 28: no straddle)
// Interior fast-path: 9 unconditional independent float4 loads (ILP).
// LN fused via LDS tree reductions; 96 = 2^5 * 3, so the tree stops at 3
// remaining partials and every thread sums those directly (s=1 step would
// silently drop index 2 — R4 bug).
__global__ __launch_bounds__(384)
void cpe_ln_kernel(const float* __restrict__ x, const float* __restrict__ w,
                   const float* __restrict__ bias, float* __restrict__ y,
                   const float* __restrict__ g, const float* __restrict__ beta,
                   bf16* __restrict__ lnout) {
    __shared__ float red[4][96];
    const int t = threadIdx.x;
    const int tpos = t / 96;
    const int cg = t - tpos * 96;
    const int c4 = cg * 4;
    const int row = blockIdx.x * 4 + tpos;   // b*784 + n
    const int b = row / N_;
    const int n = row - b * N_;
    const int py = n / WW_, px = n - py * WW_;
    const float* wc = w + c4 * 9;

    float4 acc = *(const float4*)(bias + c4);
    float4 ctr = *(const float4*)(x + (size_t)row * C_ + c4);

    if (py >= 1 && py <= 26 && px >= 1 && px <= 26) {
        const float* p0 = x + (size_t)(row - WW_ - 1) * C_ + c4;
        const float* p1 = p0 + (size_t)WW_ * C_;
        const float* p2 = p1 + (size_t)WW_ * C_;
        float4 a0 = *(const float4*)(p0);
        float4 a1 = *(const float4*)(p0 + C_);
        float4 a2 = *(const float4*)(p0 + 2 * C_);
        float4 b0 = *(const float4*)(p1);
        float4 b2 = *(const float4*)(p1 + 2 * C_);
        float4 c0 = *(const float4*)(p2);
        float4 c1 = *(const float4*)(p2 + C_);
        float4 c2 = *(const float4*)(p2 + 2 * C_);
        float4 b1 = ctr;
        #define TAP(V, TI) \
            acc.x += wc[TI] * V.x; acc.y += wc[9 + TI] * V.y; \
            acc.z += wc[18 + TI] * V.z; acc.w += wc[27 + TI] * V.w;
        TAP(a0, 0) TAP(a1, 1) TAP(a2, 2)
        TAP(b0, 3) TAP(b1, 4) TAP(b2, 5)
        TAP(c0, 6) TAP(c1, 7) TAP(c2, 8)
        #undef TAP
    } else {
        #pragma unroll
        for (int ky = 0; ky < 3; ky++) {
            int yy = py + ky - 1;
            if (yy < 0 || yy >= HH_) continue;
            #pragma unroll
            for (int kx = 0; kx < 3; kx++) {
                int xx = px + kx - 1;
                if (xx < 0 || xx >= WW_) continue;
                int tap = ky * 3 + kx;
                float4 xv = (ky == 1 && kx == 1) ? ctr
                          : *(const float4*)(x + (size_t)(b * N_ + yy * WW_ + xx) * C_ + c4);
                acc.x += wc[tap] * xv.x;
                acc.y += wc[9 + tap] * xv.y;
                acc.z += wc[18 + tap] * xv.z;
                acc.w += wc[27 + tap] * xv.w;
            }
        }
    }
    acc.x += ctr.x; acc.y += ctr.y; acc.z += ctr.z; acc.w += ctr.w;
    *(float4*)(y + (size_t)row * C_ + c4) = acc;

    // ---- fused LN over the row (96 partials = 2^5 * 3) ----
    red[tpos][cg] = acc.x + acc.y + acc.z + acc.w;
    __syncthreads();
    #pragma unroll
    for (int s = 48; s >= 3; s >>= 1) {          // 48,24,12,6,3 -> 3 partials left
        if (cg < s) red[tpos][cg] += red[tpos][cg + s];
        __syncthreads();
    }
    float mean = (red[tpos][0] + red[tpos][1] + red[tpos][2]) * (1.f / C_);
    __syncthreads();
    float dx = acc.x - mean, dy = acc.y - mean, dz = acc.z - mean, dw = acc.w - mean;
    red[tpos][cg] = dx * dx + dy * dy + dz * dz + dw * dw;
    __syncthreads();
    #pragma unroll
    for (int s = 48; s >= 3; s >>= 1) {
        if (cg < s) red[tpos][cg] += red[tpos][cg + s];
        __syncthreads();
    }
    float var = (red[tpos][0] + red[tpos][1] + red[tpos][2]) * (1.f / C_);
    float rstd = rsqrtf(var + 1e-5f);
    float4 gv = *(const float4*)(g + c4);
    float4 bv = *(const float4*)(beta + c4);
    bf16x4 ov;
    ov[0] = (bf16)(dx * rstd * gv.x + bv.x);
    ov[1] = (bf16)(dy * rstd * gv.y + bv.y);
    ov[2] = (bf16)(dz * rstd * gv.z + bv.z);
    ov[3] = (bf16)(dw * rstd * gv.w + bv.w);
    *(bf16x4*)(lnout + (size_t)row * C_ + c4) = ov;
}

// ---------------- bf16 MFMA GEMM with global_load_lds staging (m97 structure) -------
template<bool BIAS, bool GELU, bool RESID, bool OUTBF>
__global__ __launch_bounds__(256)
void gemm_kernel(const bf16* __restrict__ A, const bf16* __restrict__ Wt,
                 const float* __restrict__ bias, const float* __restrict__ resid,
                 void* __restrict__ outp, int M, int N, int K) {
    __shared__ __align__(16) bf16 As[128 * 32];
    __shared__ __align__(16) bf16 Bs[128 * 32];
    const int bm = blockIdx.y * 128, bn = blockIdx.x * 128;
    const int t = threadIdx.x;
    const int wave = t >> 6, lane = t & 63;
    const int wm = (wave & 1) * 64, wn = (wave >> 1) * 64;
    const int quad = lane >> 4, r = lane & 15;

    const int ldrow = lane >> 2;
    const int ldcol = (lane & 3) * 8;
    const bf16* ga0 = A  + (size_t)(bm + wave * 32 + ldrow) * K + ldcol;
    const bf16* ga1 = ga0 + (size_t)16 * K;
    const bf16* gb0 = Wt + (size_t)(bn + wave * 32 + ldrow) * K + ldcol;
    const bf16* gb1 = gb0 + (size_t)16 * K;
    bf16* la0 = &As[(wave * 32) * 32];
    bf16* la1 = &As[(wave * 32 + 16) * 32];
    bf16* lb0 = &Bs[(wave * 32) * 32];
    bf16* lb1 = &Bs[(wave * 32 + 16) * 32];

    f32x4 acc[4][4] = {};

    for (int k0 = 0; k0 < K; k0 += 32) {
        __syncthreads();
        gload_lds16(ga0 + k0, la0);
        gload_lds16(ga1 + k0, la1);
        gload_lds16(gb0 + k0, lb0);
        gload_lds16(gb1 + k0, lb1);
        __syncthreads();

        bf16x8 af[4], bfr[4];
        #pragma unroll
        for (int i = 0; i < 4; i++)
            af[i] = *(const bf16x8*)(&As[(wm + i * 16 + r) * 32 + quad * 8]);
        #pragma unroll
        for (int j = 0; j < 4; j++)
            bfr[j] = *(const bf16x8*)(&Bs[(wn + j * 16 + r) * 32 + quad * 8]);
        #pragma unroll
        for (int i = 0; i < 4; i++)
            #pragma unroll
            for (int j = 0; j < 4; j++)
                acc[i][j] = __builtin_amdgcn_mfma_f32_16x16x32_bf16(af[i], bfr[j], acc[i][j], 0, 0, 0);
    }

    #pragma unroll
    for (int i = 0; i < 4; i++) {
        #pragma unroll
        for (int j = 0; j < 4; j++) {
            int n = bn + wn + j * 16 + r;
            float bv = BIAS ? bias[n] : 0.f;
            #pragma unroll
            for (int e = 0; e < 4; e++) {
                int m = bm + wm + i * 16 + quad * 4 + e;
                float val = acc[i][j][e] + bv;
                if (GELU) val = 0.5f * val * (1.f + erff(val * 0.70710678118654752f));
                if (RESID) val += resid[(size_t)m * N + n];
                if (OUTBF) ((bf16*)outp)[(size_t)m * N + n] = (bf16)val;
                else       ((float*)outp)[(size_t)m * N + n] = val;
            }
        }
    }
}

// ---------------- fused channel attention (scores + softmax + apply), MFMA ----------
__global__ __launch_bounds__(256)
void attn_fused_kernel(const bf16* __restrict__ qkvb, bf16* __restrict__ outp) {
    __shared__ __align__(16) bf16 stage[4][3872];
    __shared__ float Sred[4][48][49];
    __shared__ __align__(16) bf16 attn_s[48 * 72];

    const int bh = blockIdx.x;
    const int b = bh >> 3, h = bh & 7;
    const int t = threadIdx.x;
    const int wave = t >> 6, lane = t & 63;
    const int quad = lane >> 4, r = lane & 15;
    const int tensor = lane >> 5;
    const int n_local = lane & 31;

    const size_t qkv_base = (size_t)b * N_ * 1152;
    const int toff = 384 + tensor * 384 + h * 48;

    f32x4 acc[3][3] = {};
    bf16* kT = &stage[wave][0];
    bf16* vT = &stage[wave][1936];
    bf16* myT = &stage[wave][tensor * 1936];

    for (int c = wave; c < 25; c += 4) {
        int n0 = c * 32;
        bf16 rowbuf[48];
        if (n0 + n_local < N_) {
            const uint4* src = (const uint4*)(qkvb + qkv_base + (size_t)(n0 + n_local) * 1152 + toff);
            #pragma unroll
            for (int i = 0; i < 6; i++) *(uint4*)(&rowbuf[i * 8]) = src[i];
        } else {
            #pragma unroll
            for (int i = 0; i < 48; i++) rowbuf[i] = (bf16)0.f;
        }
        #pragma unroll
        for (int d = 0; d < 48; d++) myT[d * 40 + n_local] = rowbuf[d];
        bf16x8 af[3], bfv[3];
        #pragma unroll
        for (int i = 0; i < 3; i++) af[i]  = *(const bf16x8*)(&kT[(i * 16 + r) * 40 + quad * 8]);
        #pragma unroll
        for (int j = 0; j < 3; j++) bfv[j] = *(const bf16x8*)(&vT[(j * 16 + r) * 40 + quad * 8]);
        #pragma unroll
        for (int i = 0; i < 3; i++)
            #pragma unroll
            for (int j = 0; j < 3; j++)
                acc[i][j] = __builtin_amdgcn_mfma_f32_16x16x32_bf16(af[i], bfv[j], acc[i][j], 0, 0, 0);
    }

    #pragma unroll
    for (int i = 0; i < 3; i++)
        #pragma unroll
        for (int j = 0; j < 3; j++)
            #pragma unroll
            for (int e = 0; e < 4; e++)
                Sred[wave][i * 16 + quad * 4 + e][j * 16 + r] = acc[i][j][e];
    __syncthreads();

    if (t < 48) {
        float row[48];
        float mx = -1e30f;
        #pragma unroll
        for (int e = 0; e < 48; e++) {
            float s = Sred[0][t][e] + Sred[1][t][e] + Sred[2][t][e] + Sred[3][t][e];
            s *= 0.14433756729740644f;
            row[e] = s;
            mx = fmaxf(mx, s);
        }
        float sum = 0.f;
        #pragma unroll
        for (int e = 0; e < 48; e++) { float ex = __expf(row[e] - mx); row[e] = ex; sum += ex; }
        float inv = 1.f / sum;
        #pragma unroll
        for (int e = 0; e < 48; e++) attn_s[t * 72 + e] = (bf16)(row[e] * inv);
        #pragma unroll
        for (int e = 48; e < 64; e++) attn_s[t * 72 + e] = (bf16)0.f;
    }
    __syncthreads();

    const bf16* qbase = qkvb + qkv_base + h * 48;
    for (int nt = wave; nt < 49; nt += 4) {
        int n0 = nt * 16;
        f32x4 oacc[3] = {};
        #pragma unroll
        for (int kc = 0; kc < 2; kc++) {
            bf16x8 bq = *(const bf16x8*)(qbase + (size_t)(n0 + r) * 1152 + kc * 32 + quad * 8);
            #pragma unroll
            for (int i = 0; i < 3; i++) {
                bf16x8 aa = *(const bf16x8*)(&attn_s[(i * 16 + r) * 72 + kc * 32 + quad * 8]);
                oacc[i] = __builtin_amdgcn_mfma_f32_16x16x32_bf16(aa, bq, oacc[i], 0, 0, 0);
            }
        }
        #pragma unroll
        for (int i = 0; i < 3; i++) {
            bf16x4 ov;
            #pragma unroll
            for (int e = 0; e < 4; e++) ov[e] = (bf16)oacc[i][e];
            *(bf16x4*)(outp + (size_t)(b * N_ + n0 + r) * 384 + h * 48 + i * 16 + quad * 4) = ov;
        }
    }
}

// ---------------- launch ----------------
extern "C" void kernel_launch(void* const* d_in, const int* in_sizes, int n_in,
                              void* d_out, int out_size, void* d_ws, size_t ws_size,
                              hipStream_t stream) {
    const float* x      = (const float*)d_in[0];
    const float* cpe0_w = (const float*)d_in[3];
    const float* cpe0_b = (const float*)d_in[4];
    const float* cpe1_w = (const float*)d_in[5];
    const float* cpe1_b = (const float*)d_in[6];
    const float* n1g    = (const float*)d_in[7];
    const float* n1b    = (const float*)d_in[8];
    const float* qkv_w  = (const float*)d_in[9];
    const float* proj_w = (const float*)d_in[10];
    const float* proj_b = (const float*)d_in[11];
    const float* n2g    = (const float*)d_in[12];
    const float* n2b    = (const float*)d_in[13];
    const float* fc1_w  = (const float*)d_in[14];
    const float* fc1_b  = (const float*)d_in[15];
    const float* fc2_w  = (const float*)d_in[16];
    const float* fc2_b  = (const float*)d_in[17];

    char* ws = (char*)d_ws;
    size_t off = 0;
    bf16* cur    = (bf16*)(ws + off); off += (size_t)M_ * C_ * 2;
    bf16* qkvb   = (bf16*)(ws + off);
    float* x3    = (float*)qkvb;
    off += (size_t)M_ * 1152 * 2;
    bf16* hbuf   = (bf16*)(ws + off); off += (size_t)M_ * HID_ * 2;
    bf16* qkv_wb  = (bf16*)(ws + off); off += (size_t)1152 * 384 * 2;
    bf16* proj_wb = (bf16*)(ws + off); off += (size_t)384 * 384 * 2;
    bf16* fc1_wb  = (bf16*)(ws + off); off += (size_t)HID_ * 384 * 2;
    bf16* fc2_wb  = (bf16*)(ws + off); off += (size_t)384 * HID_ * 2;
    float* out = (float*)d_out;   // doubles as x1/x2 trunk buffer

    const int na = 442368, nb = 147456, nc = 589824, nd = 589824;
    convert4_kernel<<<(na + nb + nc + nd + 255) / 256, 256, 0, stream>>>(
        qkv_w, na, proj_w, nb, fc1_w, nc, fc2_w, nd, qkv_wb);

    // CPE0 + LN1: x -> out (x1, fp32) and cur (bf16)
    cpe_ln_kernel<<<M_ / 4, 384, 0, stream>>>(x, cpe0_w, cpe0_b, out, n1g, n1b, cur);
    // qkv: cur @ qkv_w^T -> qkvb  (M x 1152, K=384)
    gemm_kernel<false, false, false, true><<<dim3(1152 / 128, M_ / 128), 256, 0, stream>>>(
        cur, qkv_wb, nullptr, nullptr, qkvb, M_, 1152, 384);
    // fused channel attention -> cur
    attn_fused_kernel<<<256, 256, 0, stream>>>(qkvb, cur);
    // proj + bias + residual -> out (fp32)
    gemm_kernel<true, false, true, false><<<dim3(384 / 128, M_ / 128), 256, 0, stream>>>(
        cur, proj_wb, proj_b, out, out, M_, 384, 384);
    // CPE1 + LN2: out (x2) -> x3 (fp32) and cur (bf16)
    cpe_ln_kernel<<<M_ / 4, 384, 0, stream>>>(out, cpe1_w, cpe1_b, x3, n2g, n2b, cur);
    // fc1 + bias + gelu -> hbuf (bf16), M x 1536, K=384
    gemm_kernel<true, true, false, true><<<dim3(HID_ / 128, M_ / 128), 256, 0, stream>>>(
        cur, fc1_wb, fc1_b, nullptr, hbuf, M_, HID_, 384);
    // fc2 + bias + residual x3 -> d_out (fp32), M x 384, K=1536
    gemm_kernel<true, false, true, false><<<dim3(384 / 128, M_ / 128), 256, 0, stream>>>(
        hbuf, fc2_wb, fc2_b, x3, out, M_, 384, HID_);
}

// Round 6
// 451.228 us; speedup vs baseline: 1.6677x; 1.0619x over previous
//
#include <hip/hip_runtime.h>
#include <hip/hip_bf16.h>
#include <math.h>
#include <stdint.h>

#define B_     32
#define HH_    28
#define WW_    28
#define N_     784
#define C_     384
#define M_     25088      // B_*N_
#define HEADS_ 8
#define HD_    48
#define HID_   1536

typedef __bf16 bf16;
typedef __attribute__((ext_vector_type(8))) __bf16 bf16x8;
typedef __attribute__((ext_vector_type(4))) __bf16 bf16x4;
typedef __attribute__((ext_vector_type(4))) float f32x4;

// async global->LDS, 16B per lane; LDS dest = wave-uniform base + lane*16
__device__ __forceinline__ void gload_lds16(const void* g, void* l) {
    __builtin_amdgcn_global_load_lds(
        (const __attribute__((address_space(1))) unsigned int*)g,
        (__attribute__((address_space(3))) unsigned int*)(uintptr_t)l,
        16, 0, 0);
}

// ---------------- weights fp32 -> bf16, all four in one launch ----------------
__global__ void convert4_kernel(const float* __restrict__ a, int na,
                                const float* __restrict__ b, int nb,
                                const float* __restrict__ c, int nc,
                                const float* __restrict__ d, int nd,
                                bf16* __restrict__ out) {
    int i = blockIdx.x * 256 + threadIdx.x;
    int j = i;
    const float* src;
    if (j < na) src = a + j;
    else { j -= na;
        if (j < nb) src = b + j;
        else { j -= nb;
            if (j < nc) src = c + j;
            else { j -= nc;
                if (j >= nd) return;
                src = d + j; } } }
    out[i] = (bf16)(*src);
}

// ------- depthwise 3x3 conv + bias + residual, fused LayerNorm -> bf16 -------
__global__ __launch_bounds__(384)
void cpe_ln_kernel(const float* __restrict__ x, const float* __restrict__ w,
                   const float* __restrict__ bias, float* __restrict__ y,
                   const float* __restrict__ g, const float* __restrict__ beta,
                   bf16* __restrict__ lnout) {
    __shared__ float red[4][96];
    const int t = threadIdx.x;
    const int tpos = t / 96;
    const int cg = t - tpos * 96;
    const int c4 = cg * 4;
    const int row = blockIdx.x * 4 + tpos;   // b*784 + n
    const int b = row / N_;
    const int n = row - b * N_;
    const int py = n / WW_, px = n - py * WW_;
    const float* wc = w + c4 * 9;

    float4 acc = *(const float4*)(bias + c4);
    float4 ctr = *(const float4*)(x + (size_t)row * C_ + c4);

    if (py >= 1 && py <= 26 && px >= 1 && px <= 26) {
        const float* p0 = x + (size_t)(row - WW_ - 1) * C_ + c4;
        const float* p1 = p0 + (size_t)WW_ * C_;
        const float* p2 = p1 + (size_t)WW_ * C_;
        float4 a0 = *(const float4*)(p0);
        float4 a1 = *(const float4*)(p0 + C_);
        float4 a2 = *(const float4*)(p0 + 2 * C_);
        float4 b0 = *(const float4*)(p1);
        float4 b2 = *(const float4*)(p1 + 2 * C_);
        float4 c0 = *(const float4*)(p2);
        float4 c1 = *(const float4*)(p2 + C_);
        float4 c2 = *(const float4*)(p2 + 2 * C_);
        float4 b1 = ctr;
        #define TAP(V, TI) \
            acc.x += wc[TI] * V.x; acc.y += wc[9 + TI] * V.y; \
            acc.z += wc[18 + TI] * V.z; acc.w += wc[27 + TI] * V.w;
        TAP(a0, 0) TAP(a1, 1) TAP(a2, 2)
        TAP(b0, 3) TAP(b1, 4) TAP(b2, 5)
        TAP(c0, 6) TAP(c1, 7) TAP(c2, 8)
        #undef TAP
    } else {
        #pragma unroll
        for (int ky = 0; ky < 3; ky++) {
            int yy = py + ky - 1;
            if (yy < 0 || yy >= HH_) continue;
            #pragma unroll
            for (int kx = 0; kx < 3; kx++) {
                int xx = px + kx - 1;
                if (xx < 0 || xx >= WW_) continue;
                int tap = ky * 3 + kx;
                float4 xv = (ky == 1 && kx == 1) ? ctr
                          : *(const float4*)(x + (size_t)(b * N_ + yy * WW_ + xx) * C_ + c4);
                acc.x += wc[tap] * xv.x;
                acc.y += wc[9 + tap] * xv.y;
                acc.z += wc[18 + tap] * xv.z;
                acc.w += wc[27 + tap] * xv.w;
            }
        }
    }
    acc.x += ctr.x; acc.y += ctr.y; acc.z += ctr.z; acc.w += ctr.w;
    *(float4*)(y + (size_t)row * C_ + c4) = acc;

    // ---- fused LN over the row (96 partials = 2^5 * 3; stop tree at 3) ----
    red[tpos][cg] = acc.x + acc.y + acc.z + acc.w;
    __syncthreads();
    #pragma unroll
    for (int s = 48; s >= 3; s >>= 1) {
        if (cg < s) red[tpos][cg] += red[tpos][cg + s];
        __syncthreads();
    }
    float mean = (red[tpos][0] + red[tpos][1] + red[tpos][2]) * (1.f / C_);
    __syncthreads();
    float dx = acc.x - mean, dy = acc.y - mean, dz = acc.z - mean, dw = acc.w - mean;
    red[tpos][cg] = dx * dx + dy * dy + dz * dz + dw * dw;
    __syncthreads();
    #pragma unroll
    for (int s = 48; s >= 3; s >>= 1) {
        if (cg < s) red[tpos][cg] += red[tpos][cg + s];
        __syncthreads();
    }
    float var = (red[tpos][0] + red[tpos][1] + red[tpos][2]) * (1.f / C_);
    float rstd = rsqrtf(var + 1e-5f);
    float4 gv = *(const float4*)(g + c4);
    float4 bv = *(const float4*)(beta + c4);
    bf16x4 ov;
    ov[0] = (bf16)(dx * rstd * gv.x + bv.x);
    ov[1] = (bf16)(dy * rstd * gv.y + bv.y);
    ov[2] = (bf16)(dz * rstd * gv.z + bv.z);
    ov[3] = (bf16)(dw * rstd * gv.w + bv.w);
    *(bf16x4*)(lnout + (size_t)row * C_ + c4) = ov;
}

// -------- bf16 MFMA GEMM, double-buffered global_load_lds staging --------
// 128x128 tile, BK=32, 256 thr. LDS 2x(8+8) KB = 32 KB -> ~5 blocks/CU.
// One barrier per K-iter; next tile's loads issued before consuming current,
// so load latency overlaps the 16 MFMAs (prefetch shadow).
template<bool BIAS, bool GELU, bool RESID, bool OUTBF>
__global__ __launch_bounds__(256)
void gemm_kernel(const bf16* __restrict__ A, const bf16* __restrict__ Wt,
                 const float* __restrict__ bias, const float* __restrict__ resid,
                 void* __restrict__ outp, int M, int N, int K) {
    __shared__ __align__(16) bf16 As[2 * 128 * 32];
    __shared__ __align__(16) bf16 Bs[2 * 128 * 32];
    const int bm = blockIdx.y * 128, bn = blockIdx.x * 128;
    const int t = threadIdx.x;
    const int wave = t >> 6, lane = t & 63;
    const int wm = (wave & 1) * 64, wn = (wave >> 1) * 64;
    const int quad = lane >> 4, r = lane & 15;

    // staging: wave w covers tile rows [w*32, w*32+32); lane i -> base + 16B*i
    const int ldrow = lane >> 2;            // 0..15
    const int ldcol = (lane & 3) * 8;       // bf16 elements
    const bf16* ga0 = A  + (size_t)(bm + wave * 32 + ldrow) * K + ldcol;
    const bf16* ga1 = ga0 + (size_t)16 * K;
    const bf16* gb0 = Wt + (size_t)(bn + wave * 32 + ldrow) * K + ldcol;
    const bf16* gb1 = gb0 + (size_t)16 * K;
    const int lbase = wave * 32 * 32;       // element offset of wave's region

    f32x4 acc[4][4] = {};

    // prologue: stage k0=0 into buffer 0
    gload_lds16(ga0, &As[lbase]);
    gload_lds16(ga1, &As[lbase + 512]);
    gload_lds16(gb0, &Bs[lbase]);
    gload_lds16(gb1, &Bs[lbase + 512]);

    int buf = 0;
    for (int k0 = 0; k0 < K; k0 += 32) {
        __syncthreads();   // drains loads into buf; WAR-protects buf^1 (read last iter)
        if (k0 + 32 < K) {
            const int nb = (buf ^ 1) * 4096;
            gload_lds16(ga0 + k0 + 32, &As[nb + lbase]);
            gload_lds16(ga1 + k0 + 32, &As[nb + lbase + 512]);
            gload_lds16(gb0 + k0 + 32, &Bs[nb + lbase]);
            gload_lds16(gb1 + k0 + 32, &Bs[nb + lbase + 512]);
        }
        const bf16* as = &As[buf * 4096];
        const bf16* bs = &Bs[buf * 4096];
        bf16x8 af[4], bfr[4];
        #pragma unroll
        for (int i = 0; i < 4; i++)
            af[i] = *(const bf16x8*)(&as[(wm + i * 16 + r) * 32 + quad * 8]);
        #pragma unroll
        for (int j = 0; j < 4; j++)
            bfr[j] = *(const bf16x8*)(&bs[(wn + j * 16 + r) * 32 + quad * 8]);
        #pragma unroll
        for (int i = 0; i < 4; i++)
            #pragma unroll
            for (int j = 0; j < 4; j++)
                acc[i][j] = __builtin_amdgcn_mfma_f32_16x16x32_bf16(af[i], bfr[j], acc[i][j], 0, 0, 0);
        buf ^= 1;
    }

    // epilogue: C/D layout col = lane&15, row = quad*4 + e
    #pragma unroll
    for (int i = 0; i < 4; i++) {
        #pragma unroll
        for (int j = 0; j < 4; j++) {
            int n = bn + wn + j * 16 + r;
            float bv = BIAS ? bias[n] : 0.f;
            #pragma unroll
            for (int e = 0; e < 4; e++) {
                int m = bm + wm + i * 16 + quad * 4 + e;
                float val = acc[i][j][e] + bv;
                if (GELU) val = 0.5f * val * (1.f + erff(val * 0.70710678118654752f));
                if (RESID) val += resid[(size_t)m * N + n];
                if (OUTBF) ((bf16*)outp)[(size_t)m * N + n] = (bf16)val;
                else       ((float*)outp)[(size_t)m * N + n] = val;
            }
        }
    }
}

// ---------------- fused channel attention (scores + softmax + apply), MFMA ----------
__global__ __launch_bounds__(256)
void attn_fused_kernel(const bf16* __restrict__ qkvb, bf16* __restrict__ outp) {
    __shared__ __align__(16) bf16 stage[4][3872];
    __shared__ float Sred[4][48][49];
    __shared__ __align__(16) bf16 attn_s[48 * 72];

    const int bh = blockIdx.x;
    const int b = bh >> 3, h = bh & 7;
    const int t = threadIdx.x;
    const int wave = t >> 6, lane = t & 63;
    const int quad = lane >> 4, r = lane & 15;
    const int tensor = lane >> 5;
    const int n_local = lane & 31;

    const size_t qkv_base = (size_t)b * N_ * 1152;
    const int toff = 384 + tensor * 384 + h * 48;

    f32x4 acc[3][3] = {};
    bf16* kT = &stage[wave][0];
    bf16* vT = &stage[wave][1936];
    bf16* myT = &stage[wave][tensor * 1936];

    for (int c = wave; c < 25; c += 4) {
        int n0 = c * 32;
        bf16 rowbuf[48];
        if (n0 + n_local < N_) {
            const uint4* src = (const uint4*)(qkvb + qkv_base + (size_t)(n0 + n_local) * 1152 + toff);
            #pragma unroll
            for (int i = 0; i < 6; i++) *(uint4*)(&rowbuf[i * 8]) = src[i];
        } else {
            #pragma unroll
            for (int i = 0; i < 48; i++) rowbuf[i] = (bf16)0.f;
        }
        #pragma unroll
        for (int d = 0; d < 48; d++) myT[d * 40 + n_local] = rowbuf[d];
        bf16x8 af[3], bfv[3];
        #pragma unroll
        for (int i = 0; i < 3; i++) af[i]  = *(const bf16x8*)(&kT[(i * 16 + r) * 40 + quad * 8]);
        #pragma unroll
        for (int j = 0; j < 3; j++) bfv[j] = *(const bf16x8*)(&vT[(j * 16 + r) * 40 + quad * 8]);
        #pragma unroll
        for (int i = 0; i < 3; i++)
            #pragma unroll
            for (int j = 0; j < 3; j++)
                acc[i][j] = __builtin_amdgcn_mfma_f32_16x16x32_bf16(af[i], bfv[j], acc[i][j], 0, 0, 0);
    }

    #pragma unroll
    for (int i = 0; i < 3; i++)
        #pragma unroll
        for (int j = 0; j < 3; j++)
            #pragma unroll
            for (int e = 0; e < 4; e++)
                Sred[wave][i * 16 + quad * 4 + e][j * 16 + r] = acc[i][j][e];
    __syncthreads();

    if (t < 48) {
        float row[48];
        float mx = -1e30f;
        #pragma unroll
        for (int e = 0; e < 48; e++) {
            float s = Sred[0][t][e] + Sred[1][t][e] + Sred[2][t][e] + Sred[3][t][e];
            s *= 0.14433756729740644f;
            row[e] = s;
            mx = fmaxf(mx, s);
        }
        float sum = 0.f;
        #pragma unroll
        for (int e = 0; e < 48; e++) { float ex = __expf(row[e] - mx); row[e] = ex; sum += ex; }
        float inv = 1.f / sum;
        #pragma unroll
        for (int e = 0; e < 48; e++) attn_s[t * 72 + e] = (bf16)(row[e] * inv);
        #pragma unroll
        for (int e = 48; e < 64; e++) attn_s[t * 72 + e] = (bf16)0.f;
    }
    __syncthreads();

    const bf16* qbase = qkvb + qkv_base + h * 48;
    for (int nt = wave; nt < 49; nt += 4) {
        int n0 = nt * 16;
        f32x4 oacc[3] = {};
        #pragma unroll
        for (int kc = 0; kc < 2; kc++) {
            bf16x8 bq = *(const bf16x8*)(qbase + (size_t)(n0 + r) * 1152 + kc * 32 + quad * 8);
            #pragma unroll
            for (int i = 0; i < 3; i++) {
                bf16x8 aa = *(const bf16x8*)(&attn_s[(i * 16 + r) * 72 + kc * 32 + quad * 8]);
                oacc[i] = __builtin_amdgcn_mfma_f32_16x16x32_bf16(aa, bq, oacc[i], 0, 0, 0);
            }
        }
        #pragma unroll
        for (int i = 0; i < 3; i++) {
            bf16x4 ov;
            #pragma unroll
            for (int e = 0; e < 4; e++) ov[e] = (bf16)oacc[i][e];
            *(bf16x4*)(outp + (size_t)(b * N_ + n0 + r) * 384 + h * 48 + i * 16 + quad * 4) = ov;
        }
    }
}

// ---------------- launch ----------------
extern "C" void kernel_launch(void* const* d_in, const int* in_sizes, int n_in,
                              void* d_out, int out_size, void* d_ws, size_t ws_size,
                              hipStream_t stream) {
    const float* x      = (const float*)d_in[0];
    const float* cpe0_w = (const float*)d_in[3];
    const float* cpe0_b = (const float*)d_in[4];
    const float* cpe1_w = (const float*)d_in[5];
    const float* cpe1_b = (const float*)d_in[6];
    const float* n1g    = (const float*)d_in[7];
    const float* n1b    = (const float*)d_in[8];
    const float* qkv_w  = (const float*)d_in[9];
    const float* proj_w = (const float*)d_in[10];
    const float* proj_b = (const float*)d_in[11];
    const float* n2g    = (const float*)d_in[12];
    const float* n2b    = (const float*)d_in[13];
    const float* fc1_w  = (const float*)d_in[14];
    const float* fc1_b  = (const float*)d_in[15];
    const float* fc2_w  = (const float*)d_in[16];
    const float* fc2_b  = (const float*)d_in[17];

    char* ws = (char*)d_ws;
    size_t off = 0;
    bf16* cur    = (bf16*)(ws + off); off += (size_t)M_ * C_ * 2;
    bf16* qkvb   = (bf16*)(ws + off);
    float* x3    = (float*)qkvb;
    off += (size_t)M_ * 1152 * 2;
    bf16* hbuf   = (bf16*)(ws + off); off += (size_t)M_ * HID_ * 2;
    bf16* qkv_wb  = (bf16*)(ws + off); off += (size_t)1152 * 384 * 2;
    bf16* proj_wb = (bf16*)(ws + off); off += (size_t)384 * 384 * 2;
    bf16* fc1_wb  = (bf16*)(ws + off); off += (size_t)HID_ * 384 * 2;
    bf16* fc2_wb  = (bf16*)(ws + off); off += (size_t)384 * HID_ * 2;
    float* out = (float*)d_out;   // doubles as x1/x2 trunk buffer

    const int na = 442368, nb = 147456, nc = 589824, nd = 589824;
    convert4_kernel<<<(na + nb + nc + nd + 255) / 256, 256, 0, stream>>>(
        qkv_w, na, proj_w, nb, fc1_w, nc, fc2_w, nd, qkv_wb);

    // CPE0 + LN1: x -> out (x1, fp32) and cur (bf16)
    cpe_ln_kernel<<<M_ / 4, 384, 0, stream>>>(x, cpe0_w, cpe0_b, out, n1g, n1b, cur);
    // qkv: cur @ qkv_w^T -> qkvb  (M x 1152, K=384)
    gemm_kernel<false, false, false, true><<<dim3(1152 / 128, M_ / 128), 256, 0, stream>>>(
        cur, qkv_wb, nullptr, nullptr, qkvb, M_, 1152, 384);
    // fused channel attention -> cur
    attn_fused_kernel<<<256, 256, 0, stream>>>(qkvb, cur);
    // proj + bias + residual -> out (fp32)
    gemm_kernel<true, false, true, false><<<dim3(384 / 128, M_ / 128), 256, 0, stream>>>(
        cur, proj_wb, proj_b, out, out, M_, 384, 384);
    // CPE1 + LN2: out (x2) -> x3 (fp32) and cur (bf16)
    cpe_ln_kernel<<<M_ / 4, 384, 0, stream>>>(out, cpe1_w, cpe1_b, x3, n2g, n2b, cur);
    // fc1 + bias + gelu -> hbuf (bf16), M x 1536, K=384
    gemm_kernel<true, true, false, true><<<dim3(HID_ / 128, M_ / 128), 256, 0, stream>>>(
        cur, fc1_wb, fc1_b, nullptr, hbuf, M_, HID_, 384);
    // fc2 + bias + residual x3 -> d_out (fp32), M x 384, K=1536
    gemm_kernel<true, false, true, false><<<dim3(384 / 128, M_ / 128), 256, 0, stream>>>(
        hbuf, fc2_wb, fc2_b, x3, out, M_, 384, HID_);
}

// Round 7
// 419.855 us; speedup vs baseline: 1.7923x; 1.0747x over previous
//
#include <hip/hip_runtime.h>
#include <hip/hip_bf16.h>
#include <math.h>
#include <stdint.h>

#define B_     32
#define HH_    28
#define WW_    28
#define N_     784
#define C_     384
#define M_     25088      // B_*N_
#define HEADS_ 8
#define HD_    48
#define HID_   1536

typedef __bf16 bf16;
typedef __attribute__((ext_vector_type(8))) __bf16 bf16x8;
typedef __attribute__((ext_vector_type(4))) __bf16 bf16x4;
typedef __attribute__((ext_vector_type(4))) float f32x4;

// async global->LDS, 16B per lane; LDS dest = wave-uniform base + lane*16
__device__ __forceinline__ void gload_lds16(const void* g, void* l) {
    __builtin_amdgcn_global_load_lds(
        (const __attribute__((address_space(1))) unsigned int*)g,
        (__attribute__((address_space(3))) unsigned int*)(uintptr_t)l,
        16, 0, 0);
}

// ---------------- weights fp32 -> bf16, all four in one launch ----------------
__global__ void convert4_kernel(const float* __restrict__ a, int na,
                                const float* __restrict__ b, int nb,
                                const float* __restrict__ c, int nc,
                                const float* __restrict__ d, int nd,
                                bf16* __restrict__ out) {
    int i = blockIdx.x * 256 + threadIdx.x;
    int j = i;
    const float* src;
    if (j < na) src = a + j;
    else { j -= na;
        if (j < nb) src = b + j;
        else { j -= nb;
            if (j < nc) src = c + j;
            else { j -= nc;
                if (j >= nd) return;
                src = d + j; } } }
    out[i] = (bf16)(*src);
}

// ------- depthwise 3x3 conv + bias + residual, fused LayerNorm -> bf16 -------
__global__ __launch_bounds__(384)
void cpe_ln_kernel(const float* __restrict__ x, const float* __restrict__ w,
                   const float* __restrict__ bias, float* __restrict__ y,
                   const float* __restrict__ g, const float* __restrict__ beta,
                   bf16* __restrict__ lnout) {
    __shared__ float red[4][96];
    const int t = threadIdx.x;
    const int tpos = t / 96;
    const int cg = t - tpos * 96;
    const int c4 = cg * 4;
    const int row = blockIdx.x * 4 + tpos;   // b*784 + n
    const int b = row / N_;
    const int n = row - b * N_;
    const int py = n / WW_, px = n - py * WW_;
    const float* wc = w + c4 * 9;

    float4 acc = *(const float4*)(bias + c4);
    float4 ctr = *(const float4*)(x + (size_t)row * C_ + c4);

    if (py >= 1 && py <= 26 && px >= 1 && px <= 26) {
        const float* p0 = x + (size_t)(row - WW_ - 1) * C_ + c4;
        const float* p1 = p0 + (size_t)WW_ * C_;
        const float* p2 = p1 + (size_t)WW_ * C_;
        float4 a0 = *(const float4*)(p0);
        float4 a1 = *(const float4*)(p0 + C_);
        float4 a2 = *(const float4*)(p0 + 2 * C_);
        float4 b0 = *(const float4*)(p1);
        float4 b2 = *(const float4*)(p1 + 2 * C_);
        float4 c0 = *(const float4*)(p2);
        float4 c1 = *(const float4*)(p2 + C_);
        float4 c2 = *(const float4*)(p2 + 2 * C_);
        float4 b1 = ctr;
        #define TAP(V, TI) \
            acc.x += wc[TI] * V.x; acc.y += wc[9 + TI] * V.y; \
            acc.z += wc[18 + TI] * V.z; acc.w += wc[27 + TI] * V.w;
        TAP(a0, 0) TAP(a1, 1) TAP(a2, 2)
        TAP(b0, 3) TAP(b1, 4) TAP(b2, 5)
        TAP(c0, 6) TAP(c1, 7) TAP(c2, 8)
        #undef TAP
    } else {
        #pragma unroll
        for (int ky = 0; ky < 3; ky++) {
            int yy = py + ky - 1;
            if (yy < 0 || yy >= HH_) continue;
            #pragma unroll
            for (int kx = 0; kx < 3; kx++) {
                int xx = px + kx - 1;
                if (xx < 0 || xx >= WW_) continue;
                int tap = ky * 3 + kx;
                float4 xv = (ky == 1 && kx == 1) ? ctr
                          : *(const float4*)(x + (size_t)(b * N_ + yy * WW_ + xx) * C_ + c4);
                acc.x += wc[tap] * xv.x;
                acc.y += wc[9 + tap] * xv.y;
                acc.z += wc[18 + tap] * xv.z;
                acc.w += wc[27 + tap] * xv.w;
            }
        }
    }
    acc.x += ctr.x; acc.y += ctr.y; acc.z += ctr.z; acc.w += ctr.w;
    *(float4*)(y + (size_t)row * C_ + c4) = acc;

    // ---- fused LN over the row (96 partials = 2^5 * 3; stop tree at 3) ----
    red[tpos][cg] = acc.x + acc.y + acc.z + acc.w;
    __syncthreads();
    #pragma unroll
    for (int s = 48; s >= 3; s >>= 1) {
        if (cg < s) red[tpos][cg] += red[tpos][cg + s];
        __syncthreads();
    }
    float mean = (red[tpos][0] + red[tpos][1] + red[tpos][2]) * (1.f / C_);
    __syncthreads();
    float dx = acc.x - mean, dy = acc.y - mean, dz = acc.z - mean, dw = acc.w - mean;
    red[tpos][cg] = dx * dx + dy * dy + dz * dz + dw * dw;
    __syncthreads();
    #pragma unroll
    for (int s = 48; s >= 3; s >>= 1) {
        if (cg < s) red[tpos][cg] += red[tpos][cg + s];
        __syncthreads();
    }
    float var = (red[tpos][0] + red[tpos][1] + red[tpos][2]) * (1.f / C_);
    float rstd = rsqrtf(var + 1e-5f);
    float4 gv = *(const float4*)(g + c4);
    float4 bv = *(const float4*)(beta + c4);
    bf16x4 ov;
    ov[0] = (bf16)(dx * rstd * gv.x + bv.x);
    ov[1] = (bf16)(dy * rstd * gv.y + bv.y);
    ov[2] = (bf16)(dz * rstd * gv.z + bv.z);
    ov[3] = (bf16)(dw * rstd * gv.w + bv.w);
    *(bf16x4*)(lnout + (size_t)row * C_ + c4) = ov;
}

// -------- bf16 MFMA GEMM: 3-stage ring buffer, raw barrier + explicit vmcnt --------
// 128x128 tile, BK=32, 256 thr, LDS 3x16 KB = 48 KB (3 blocks/CU).
// Per iter: s_waitcnt vmcnt(4) (oldest stage landed; next stage stays in flight),
// raw s_barrier (safe: all ds_reads are consumed by MFMAs pre-barrier, so lgkm is
// drained by the compiler before the consuming MFMA), issue stage i+2, compute
// stage i. Shadow = 2 iterations; never drains to vmcnt(0) until the peeled last
// stage. XCD swizzle: flat id f -> (f%8 cycles m-rows) so the blocks sharing an
// A-row land on one XCD -> A re-reads hit that XCD's L2.
template<bool BIAS, bool GELU, bool RESID, bool OUTBF>
__global__ __launch_bounds__(256)
void gemm_kernel(const bf16* __restrict__ A, const bf16* __restrict__ Wt,
                 const float* __restrict__ bias, const float* __restrict__ resid,
                 void* __restrict__ outp, int M, int N, int K) {
    __shared__ __align__(16) bf16 As[3 * 4096];
    __shared__ __align__(16) bf16 Bs[3 * 4096];

    // XCD-aware swizzle (bijective; tail group when nbm % 8 != 0)
    const int nbn = gridDim.x, nbm = gridDim.y;
    const int f = blockIdx.y * nbn + blockIdx.x;
    const int grp = f / (8 * nbn);
    const int rem = f - grp * 8 * nbn;
    const int rows = min(8, nbm - grp * 8);
    const int bm = (grp * 8 + rem % rows) * 128;
    const int bn = (rem / rows) * 128;

    const int t = threadIdx.x;
    const int wave = t >> 6, lane = t & 63;
    const int wm = (wave & 1) * 64, wn = (wave >> 1) * 64;
    const int quad = lane >> 4, r = lane & 15;

    // staging: wave w covers tile rows [w*32, w*32+32); lane i -> base + 16B*i
    const int ldrow = lane >> 2;
    const int ldcol = (lane & 3) * 8;
    const bf16* ga0 = A  + (size_t)(bm + wave * 32 + ldrow) * K + ldcol;
    const bf16* ga1 = ga0 + (size_t)16 * K;
    const bf16* gb0 = Wt + (size_t)(bn + wave * 32 + ldrow) * K + ldcol;
    const bf16* gb1 = gb0 + (size_t)16 * K;
    const int lbase = wave * 32 * 32;

    f32x4 acc[4][4] = {};

    // prologue: stages 0 and 1 (K assumed >= 96; all call sites are 384/1536)
    gload_lds16(ga0, &As[lbase]);
    gload_lds16(ga1, &As[lbase + 512]);
    gload_lds16(gb0, &Bs[lbase]);
    gload_lds16(gb1, &Bs[lbase + 512]);
    gload_lds16(ga0 + 32, &As[4096 + lbase]);
    gload_lds16(ga1 + 32, &As[4096 + lbase + 512]);
    gload_lds16(gb0 + 32, &Bs[4096 + lbase]);
    gload_lds16(gb1 + 32, &Bs[4096 + lbase + 512]);

    int buf = 0;
    int k0 = 0;
    for (; k0 < K - 32; k0 += 32) {
        // oldest stage (4 loads) landed; keep next stage (4) in flight
        asm volatile("s_waitcnt vmcnt(4)" ::: "memory");
        asm volatile("s_barrier" ::: "memory");
        if (k0 + 64 < K) {
            const int nb3 = (buf == 0 ? 2 : buf - 1) * 4096;   // (buf+2)%3
            gload_lds16(ga0 + k0 + 64, &As[nb3 + lbase]);
            gload_lds16(ga1 + k0 + 64, &As[nb3 + lbase + 512]);
            gload_lds16(gb0 + k0 + 64, &Bs[nb3 + lbase]);
            gload_lds16(gb1 + k0 + 64, &Bs[nb3 + lbase + 512]);
        }
        const bf16* as = &As[buf * 4096];
        const bf16* bs = &Bs[buf * 4096];
        bf16x8 af[4], bfr[4];
        #pragma unroll
        for (int i = 0; i < 4; i++)
            af[i] = *(const bf16x8*)(&as[(wm + i * 16 + r) * 32 + quad * 8]);
        #pragma unroll
        for (int j = 0; j < 4; j++)
            bfr[j] = *(const bf16x8*)(&bs[(wn + j * 16 + r) * 32 + quad * 8]);
        #pragma unroll
        for (int i = 0; i < 4; i++)
            #pragma unroll
            for (int j = 0; j < 4; j++)
                acc[i][j] = __builtin_amdgcn_mfma_f32_16x16x32_bf16(af[i], bfr[j], acc[i][j], 0, 0, 0);
        buf = (buf == 2) ? 0 : buf + 1;
    }
    // peeled last stage: only 4 loads outstanding -> must drain fully
    {
        asm volatile("s_waitcnt vmcnt(0)" ::: "memory");
        asm volatile("s_barrier" ::: "memory");
        const bf16* as = &As[buf * 4096];
        const bf16* bs = &Bs[buf * 4096];
        bf16x8 af[4], bfr[4];
        #pragma unroll
        for (int i = 0; i < 4; i++)
            af[i] = *(const bf16x8*)(&as[(wm + i * 16 + r) * 32 + quad * 8]);
        #pragma unroll
        for (int j = 0; j < 4; j++)
            bfr[j] = *(const bf16x8*)(&bs[(wn + j * 16 + r) * 32 + quad * 8]);
        #pragma unroll
        for (int i = 0; i < 4; i++)
            #pragma unroll
            for (int j = 0; j < 4; j++)
                acc[i][j] = __builtin_amdgcn_mfma_f32_16x16x32_bf16(af[i], bfr[j], acc[i][j], 0, 0, 0);
    }

    // epilogue: C/D layout col = lane&15, row = quad*4 + e
    #pragma unroll
    for (int i = 0; i < 4; i++) {
        #pragma unroll
        for (int j = 0; j < 4; j++) {
            int n = bn + wn + j * 16 + r;
            float bv = BIAS ? bias[n] : 0.f;
            #pragma unroll
            for (int e = 0; e < 4; e++) {
                int m = bm + wm + i * 16 + quad * 4 + e;
                float val = acc[i][j][e] + bv;
                if (GELU) val = 0.5f * val * (1.f + erff(val * 0.70710678118654752f));
                if (RESID) val += resid[(size_t)m * N + n];
                if (OUTBF) ((bf16*)outp)[(size_t)m * N + n] = (bf16)val;
                else       ((float*)outp)[(size_t)m * N + n] = val;
            }
        }
    }
}

// ---------------- fused channel attention (scores + softmax + apply), MFMA ----------
__global__ __launch_bounds__(256)
void attn_fused_kernel(const bf16* __restrict__ qkvb, bf16* __restrict__ outp) {
    __shared__ __align__(16) bf16 stage[4][3872];
    __shared__ float Sred[4][48][49];
    __shared__ __align__(16) bf16 attn_s[48 * 72];

    const int bh = blockIdx.x;
    const int b = bh >> 3, h = bh & 7;
    const int t = threadIdx.x;
    const int wave = t >> 6, lane = t & 63;
    const int quad = lane >> 4, r = lane & 15;
    const int tensor = lane >> 5;
    const int n_local = lane & 31;

    const size_t qkv_base = (size_t)b * N_ * 1152;
    const int toff = 384 + tensor * 384 + h * 48;

    f32x4 acc[3][3] = {};
    bf16* kT = &stage[wave][0];
    bf16* vT = &stage[wave][1936];
    bf16* myT = &stage[wave][tensor * 1936];

    for (int c = wave; c < 25; c += 4) {
        int n0 = c * 32;
        bf16 rowbuf[48];
        if (n0 + n_local < N_) {
            const uint4* src = (const uint4*)(qkvb + qkv_base + (size_t)(n0 + n_local) * 1152 + toff);
            #pragma unroll
            for (int i = 0; i < 6; i++) *(uint4*)(&rowbuf[i * 8]) = src[i];
        } else {
            #pragma unroll
            for (int i = 0; i < 48; i++) rowbuf[i] = (bf16)0.f;
        }
        #pragma unroll
        for (int d = 0; d < 48; d++) myT[d * 40 + n_local] = rowbuf[d];
        bf16x8 af[3], bfv[3];
        #pragma unroll
        for (int i = 0; i < 3; i++) af[i]  = *(const bf16x8*)(&kT[(i * 16 + r) * 40 + quad * 8]);
        #pragma unroll
        for (int j = 0; j < 3; j++) bfv[j] = *(const bf16x8*)(&vT[(j * 16 + r) * 40 + quad * 8]);
        #pragma unroll
        for (int i = 0; i < 3; i++)
            #pragma unroll
            for (int j = 0; j < 3; j++)
                acc[i][j] = __builtin_amdgcn_mfma_f32_16x16x32_bf16(af[i], bfv[j], acc[i][j], 0, 0, 0);
    }

    #pragma unroll
    for (int i = 0; i < 3; i++)
        #pragma unroll
        for (int j = 0; j < 3; j++)
            #pragma unroll
            for (int e = 0; e < 4; e++)
                Sred[wave][i * 16 + quad * 4 + e][j * 16 + r] = acc[i][j][e];
    __syncthreads();

    if (t < 48) {
        float row[48];
        float mx = -1e30f;
        #pragma unroll
        for (int e = 0; e < 48; e++) {
            float s = Sred[0][t][e] + Sred[1][t][e] + Sred[2][t][e] + Sred[3][t][e];
            s *= 0.14433756729740644f;
            row[e] = s;
            mx = fmaxf(mx, s);
        }
        float sum = 0.f;
        #pragma unroll
        for (int e = 0; e < 48; e++) { float ex = __expf(row[e] - mx); row[e] = ex; sum += ex; }
        float inv = 1.f / sum;
        #pragma unroll
        for (int e = 0; e < 48; e++) attn_s[t * 72 + e] = (bf16)(row[e] * inv);
        #pragma unroll
        for (int e = 48; e < 64; e++) attn_s[t * 72 + e] = (bf16)0.f;
    }
    __syncthreads();

    const bf16* qbase = qkvb + qkv_base + h * 48;
    for (int nt = wave; nt < 49; nt += 4) {
        int n0 = nt * 16;
        f32x4 oacc[3] = {};
        #pragma unroll
        for (int kc = 0; kc < 2; kc++) {
            bf16x8 bq = *(const bf16x8*)(qbase + (size_t)(n0 + r) * 1152 + kc * 32 + quad * 8);
            #pragma unroll
            for (int i = 0; i < 3; i++) {
                bf16x8 aa = *(const bf16x8*)(&attn_s[(i * 16 + r) * 72 + kc * 32 + quad * 8]);
                oacc[i] = __builtin_amdgcn_mfma_f32_16x16x32_bf16(aa, bq, oacc[i], 0, 0, 0);
            }
        }
        #pragma unroll
        for (int i = 0; i < 3; i++) {
            bf16x4 ov;
            #pragma unroll
            for (int e = 0; e < 4; e++) ov[e] = (bf16)oacc[i][e];
            *(bf16x4*)(outp + (size_t)(b * N_ + n0 + r) * 384 + h * 48 + i * 16 + quad * 4) = ov;
        }
    }
}

// ---------------- launch ----------------
extern "C" void kernel_launch(void* const* d_in, const int* in_sizes, int n_in,
                              void* d_out, int out_size, void* d_ws, size_t ws_size,
                              hipStream_t stream) {
    const float* x      = (const float*)d_in[0];
    const float* cpe0_w = (const float*)d_in[3];
    const float* cpe0_b = (const float*)d_in[4];
    const float* cpe1_w = (const float*)d_in[5];
    const float* cpe1_b = (const float*)d_in[6];
    const float* n1g    = (const float*)d_in[7];
    const float* n1b    = (const float*)d_in[8];
    const float* qkv_w  = (const float*)d_in[9];
    const float* proj_w = (const float*)d_in[10];
    const float* proj_b = (const float*)d_in[11];
    const float* n2g    = (const float*)d_in[12];
    const float* n2b    = (const float*)d_in[13];
    const float* fc1_w  = (const float*)d_in[14];
    const float* fc1_b  = (const float*)d_in[15];
    const float* fc2_w  = (const float*)d_in[16];
    const float* fc2_b  = (const float*)d_in[17];

    char* ws = (char*)d_ws;
    size_t off = 0;
    bf16* cur    = (bf16*)(ws + off); off += (size_t)M_ * C_ * 2;
    bf16* qkvb   = (bf16*)(ws + off);
    float* x3    = (float*)qkvb;
    off += (size_t)M_ * 1152 * 2;
    bf16* hbuf   = (bf16*)(ws + off); off += (size_t)M_ * HID_ * 2;
    bf16* qkv_wb  = (bf16*)(ws + off); off += (size_t)1152 * 384 * 2;
    bf16* proj_wb = (bf16*)(ws + off); off += (size_t)384 * 384 * 2;
    bf16* fc1_wb  = (bf16*)(ws + off); off += (size_t)HID_ * 384 * 2;
    bf16* fc2_wb  = (bf16*)(ws + off); off += (size_t)384 * HID_ * 2;
    float* out = (float*)d_out;   // doubles as x1/x2 trunk buffer

    const int na = 442368, nb = 147456, nc = 589824, nd = 589824;
    convert4_kernel<<<(na + nb + nc + nd + 255) / 256, 256, 0, stream>>>(
        qkv_w, na, proj_w, nb, fc1_w, nc, fc2_w, nd, qkv_wb);

    // CPE0 + LN1: x -> out (x1, fp32) and cur (bf16)
    cpe_ln_kernel<<<M_ / 4, 384, 0, stream>>>(x, cpe0_w, cpe0_b, out, n1g, n1b, cur);
    // qkv: cur @ qkv_w^T -> qkvb  (M x 1152, K=384)
    gemm_kernel<false, false, false, true><<<dim3(1152 / 128, M_ / 128), 256, 0, stream>>>(
        cur, qkv_wb, nullptr, nullptr, qkvb, M_, 1152, 384);
    // fused channel attention -> cur
    attn_fused_kernel<<<256, 256, 0, stream>>>(qkvb, cur);
    // proj + bias + residual -> out (fp32)
    gemm_kernel<true, false, true, false><<<dim3(384 / 128, M_ / 128), 256, 0, stream>>>(
        cur, proj_wb, proj_b, out, out, M_, 384, 384);
    // CPE1 + LN2: out (x2) -> x3 (fp32) and cur (bf16)
    cpe_ln_kernel<<<M_ / 4, 384, 0, stream>>>(out, cpe1_w, cpe1_b, x3, n2g, n2b, cur);
    // fc1 + bias + gelu -> hbuf (bf16), M x 1536, K=384
    gemm_kernel<true, true, false, true><<<dim3(HID_ / 128, M_ / 128), 256, 0, stream>>>(
        cur, fc1_wb, fc1_b, nullptr, hbuf, M_, HID_, 384);
    // fc2 + bias + residual x3 -> d_out (fp32), M x 384, K=1536
    gemm_kernel<true, false, true, false><<<dim3(384 / 128, M_ / 128), 256, 0, stream>>>(
        hbuf, fc2_wb, fc2_b, x3, out, M_, 384, HID_);
}

// Round 8
// 374.201 us; speedup vs baseline: 2.0109x; 1.1220x over previous
//
#include <hip/hip_runtime.h>
#include <hip/hip_bf16.h>
#include <math.h>
#include <stdint.h>

#define B_     32
#define HH_    28
#define WW_    28
#define N_     784
#define C_     384
#define M_     25088      // B_*N_
#define HEADS_ 8
#define HD_    48
#define HID_   1536

typedef __bf16 bf16;
typedef __attribute__((ext_vector_type(8))) __bf16 bf16x8;
typedef __attribute__((ext_vector_type(4))) __bf16 bf16x4;
typedef __attribute__((ext_vector_type(4))) float f32x4;

// async global->LDS, 16B per lane; LDS dest = wave-uniform base + lane*16
__device__ __forceinline__ void gload_lds16(const void* g, void* l) {
    __builtin_amdgcn_global_load_lds(
        (const __attribute__((address_space(1))) unsigned int*)g,
        (__attribute__((address_space(3))) unsigned int*)(uintptr_t)l,
        16, 0, 0);
}

// ---------------- weights fp32 -> bf16, all four in one launch ----------------
__global__ void convert4_kernel(const float* __restrict__ a, int na,
                                const float* __restrict__ b, int nb,
                                const float* __restrict__ c, int nc,
                                const float* __restrict__ d, int nd,
                                bf16* __restrict__ out) {
    int i = blockIdx.x * 256 + threadIdx.x;
    int j = i;
    const float* src;
    if (j < na) src = a + j;
    else { j -= na;
        if (j < nb) src = b + j;
        else { j -= nb;
            if (j < nc) src = c + j;
            else { j -= nc;
                if (j >= nd) return;
                src = d + j; } } }
    out[i] = (bf16)(*src);
}

// ---------------- CPE weight transpose: w[c][tap] -> wt[tap][c], both convs ---------
__global__ void wtrans_kernel(const float* __restrict__ w0, const float* __restrict__ w1,
                              float* __restrict__ wt0, float* __restrict__ wt1) {
    int i = blockIdx.x * 256 + threadIdx.x;     // 0..3455
    if (i >= C_ * 9) return;
    int c = i / 9, t = i - c * 9;
    wt0[t * C_ + c] = w0[i];
    wt1[t * C_ + c] = w1[i];
}

// ------- depthwise 3x3 conv + bias + residual, fused LayerNorm -> bf16 -------
// ONE WAVE PER ROW: lane l owns channels {l, l+64, ..., l+320}. LN reduction is a
// pure __shfl_xor butterfly — zero barriers, zero LDS. Border branch is
// wave-uniform (py/px per-row). Interior: 48 independent coalesced dword loads
// in flight. XCD-chunk swizzle: block f -> rows (f%8)*3136 + (f>>3)*4, so each
// XCD works on 4 whole images -> vertical 3x3 re-reads hit its own L2.
__global__ __launch_bounds__(256)
void cpe_ln_kernel(const float* __restrict__ x, const float* __restrict__ wt,
                   const float* __restrict__ bias, float* __restrict__ y,
                   const float* __restrict__ g, const float* __restrict__ beta,
                   bf16* __restrict__ lnout) {
    const int wave = threadIdx.x >> 6, lane = threadIdx.x & 63;
    const int f = blockIdx.x;
    const int row = (f & 7) * 3136 + (f >> 3) * 4 + wave;   // bijective over M_
    const int b = row / N_;
    const int n = row - b * N_;
    const int py = n / WW_, px = n - py * WW_;

    float acc[6], ctr[6];
    const float* xrow = x + (size_t)row * C_ + lane;
    #pragma unroll
    for (int j = 0; j < 6; j++) {
        acc[j] = bias[lane + j * 64];
        ctr[j] = xrow[j * 64];
    }

    if (py >= 1 && py <= 26 && px >= 1 && px <= 26) {
        // interior: 8 taps loaded unconditionally (center reuses ctr)
        const float* p = x + (size_t)(row - WW_ - 1) * C_ + lane;
        float v[9][6];
        #pragma unroll
        for (int t = 0; t < 9; t++) {
            if (t == 4) continue;
            const float* pt = p + ((t / 3) * WW_ + (t % 3)) * C_;
            #pragma unroll
            for (int j = 0; j < 6; j++) v[t][j] = pt[j * 64];
        }
        #pragma unroll
        for (int t = 0; t < 9; t++) {
            #pragma unroll
            for (int j = 0; j < 6; j++) {
                float xv = (t == 4) ? ctr[j] : v[t][j];
                acc[j] += wt[t * C_ + lane + j * 64] * xv;
            }
        }
    } else {
        #pragma unroll
        for (int t = 0; t < 9; t++) {
            int yy = py + t / 3 - 1, xx = px + t % 3 - 1;
            if (yy < 0 || yy >= HH_ || xx < 0 || xx >= WW_) continue;
            const float* pt = x + (size_t)(b * N_ + yy * WW_ + xx) * C_ + lane;
            #pragma unroll
            for (int j = 0; j < 6; j++)
                acc[j] += wt[t * C_ + lane + j * 64] * pt[j * 64];
        }
    }
    #pragma unroll
    for (int j = 0; j < 6; j++) acc[j] += ctr[j];

    float* yrow = y + (size_t)row * C_ + lane;
    #pragma unroll
    for (int j = 0; j < 6; j++) yrow[j * 64] = acc[j];

    // ---- LN: wave-wide butterfly, no barriers ----
    float s = 0.f;
    #pragma unroll
    for (int j = 0; j < 6; j++) s += acc[j];
    #pragma unroll
    for (int off = 1; off < 64; off <<= 1) s += __shfl_xor(s, off, 64);
    float mean = s * (1.f / C_);
    float d[6], vs = 0.f;
    #pragma unroll
    for (int j = 0; j < 6; j++) { d[j] = acc[j] - mean; vs += d[j] * d[j]; }
    #pragma unroll
    for (int off = 1; off < 64; off <<= 1) vs += __shfl_xor(vs, off, 64);
    float rstd = rsqrtf(vs * (1.f / C_) + 1e-5f);
    bf16* lrow = lnout + (size_t)row * C_ + lane;
    #pragma unroll
    for (int j = 0; j < 6; j++) {
        int c = lane + j * 64;
        lrow[j * 64] = (bf16)(d[j] * rstd * g[c] + beta[c]);
    }
}

// -------- bf16 MFMA GEMM: 3-stage ring buffer, raw barrier + explicit vmcnt --------
// (unchanged from R7 — proven correct and fast)
template<bool BIAS, bool GELU, bool RESID, bool OUTBF>
__global__ __launch_bounds__(256)
void gemm_kernel(const bf16* __restrict__ A, const bf16* __restrict__ Wt,
                 const float* __restrict__ bias, const float* __restrict__ resid,
                 void* __restrict__ outp, int M, int N, int K) {
    __shared__ __align__(16) bf16 As[3 * 4096];
    __shared__ __align__(16) bf16 Bs[3 * 4096];

    const int nbn = gridDim.x, nbm = gridDim.y;
    const int f = blockIdx.y * nbn + blockIdx.x;
    const int grp = f / (8 * nbn);
    const int rem = f - grp * 8 * nbn;
    const int rows = min(8, nbm - grp * 8);
    const int bm = (grp * 8 + rem % rows) * 128;
    const int bn = (rem / rows) * 128;

    const int t = threadIdx.x;
    const int wave = t >> 6, lane = t & 63;
    const int wm = (wave & 1) * 64, wn = (wave >> 1) * 64;
    const int quad = lane >> 4, r = lane & 15;

    const int ldrow = lane >> 2;
    const int ldcol = (lane & 3) * 8;
    const bf16* ga0 = A  + (size_t)(bm + wave * 32 + ldrow) * K + ldcol;
    const bf16* ga1 = ga0 + (size_t)16 * K;
    const bf16* gb0 = Wt + (size_t)(bn + wave * 32 + ldrow) * K + ldcol;
    const bf16* gb1 = gb0 + (size_t)16 * K;
    const int lbase = wave * 32 * 32;

    f32x4 acc[4][4] = {};

    gload_lds16(ga0, &As[lbase]);
    gload_lds16(ga1, &As[lbase + 512]);
    gload_lds16(gb0, &Bs[lbase]);
    gload_lds16(gb1, &Bs[lbase + 512]);
    gload_lds16(ga0 + 32, &As[4096 + lbase]);
    gload_lds16(ga1 + 32, &As[4096 + lbase + 512]);
    gload_lds16(gb0 + 32, &Bs[4096 + lbase]);
    gload_lds16(gb1 + 32, &Bs[4096 + lbase + 512]);

    int buf = 0;
    int k0 = 0;
    for (; k0 < K - 32; k0 += 32) {
        asm volatile("s_waitcnt vmcnt(4)" ::: "memory");
        asm volatile("s_barrier" ::: "memory");
        if (k0 + 64 < K) {
            const int nb3 = (buf == 0 ? 2 : buf - 1) * 4096;   // (buf+2)%3
            gload_lds16(ga0 + k0 + 64, &As[nb3 + lbase]);
            gload_lds16(ga1 + k0 + 64, &As[nb3 + lbase + 512]);
            gload_lds16(gb0 + k0 + 64, &Bs[nb3 + lbase]);
            gload_lds16(gb1 + k0 + 64, &Bs[nb3 + lbase + 512]);
        }
        const bf16* as = &As[buf * 4096];
        const bf16* bs = &Bs[buf * 4096];
        bf16x8 af[4], bfr[4];
        #pragma unroll
        for (int i = 0; i < 4; i++)
            af[i] = *(const bf16x8*)(&as[(wm + i * 16 + r) * 32 + quad * 8]);
        #pragma unroll
        for (int j = 0; j < 4; j++)
            bfr[j] = *(const bf16x8*)(&bs[(wn + j * 16 + r) * 32 + quad * 8]);
        #pragma unroll
        for (int i = 0; i < 4; i++)
            #pragma unroll
            for (int j = 0; j < 4; j++)
                acc[i][j] = __builtin_amdgcn_mfma_f32_16x16x32_bf16(af[i], bfr[j], acc[i][j], 0, 0, 0);
        buf = (buf == 2) ? 0 : buf + 1;
    }
    {
        asm volatile("s_waitcnt vmcnt(0)" ::: "memory");
        asm volatile("s_barrier" ::: "memory");
        const bf16* as = &As[buf * 4096];
        const bf16* bs = &Bs[buf * 4096];
        bf16x8 af[4], bfr[4];
        #pragma unroll
        for (int i = 0; i < 4; i++)
            af[i] = *(const bf16x8*)(&as[(wm + i * 16 + r) * 32 + quad * 8]);
        #pragma unroll
        for (int j = 0; j < 4; j++)
            bfr[j] = *(const bf16x8*)(&bs[(wn + j * 16 + r) * 32 + quad * 8]);
        #pragma unroll
        for (int i = 0; i < 4; i++)
            #pragma unroll
            for (int j = 0; j < 4; j++)
                acc[i][j] = __builtin_amdgcn_mfma_f32_16x16x32_bf16(af[i], bfr[j], acc[i][j], 0, 0, 0);
    }

    #pragma unroll
    for (int i = 0; i < 4; i++) {
        #pragma unroll
        for (int j = 0; j < 4; j++) {
            int n = bn + wn + j * 16 + r;
            float bv = BIAS ? bias[n] : 0.f;
            #pragma unroll
            for (int e = 0; e < 4; e++) {
                int m = bm + wm + i * 16 + quad * 4 + e;
                float val = acc[i][j][e] + bv;
                if (GELU) val = 0.5f * val * (1.f + erff(val * 0.70710678118654752f));
                if (RESID) val += resid[(size_t)m * N + n];
                if (OUTBF) ((bf16*)outp)[(size_t)m * N + n] = (bf16)val;
                else       ((float*)outp)[(size_t)m * N + n] = val;
            }
        }
    }
}

// ---------------- fused channel attention (scores + softmax + apply), MFMA ----------
__global__ __launch_bounds__(256)
void attn_fused_kernel(const bf16* __restrict__ qkvb, bf16* __restrict__ outp) {
    __shared__ __align__(16) bf16 stage[4][3872];
    __shared__ float Sred[4][48][49];
    __shared__ __align__(16) bf16 attn_s[48 * 72];

    const int bh = blockIdx.x;
    const int b = bh >> 3, h = bh & 7;
    const int t = threadIdx.x;
    const int wave = t >> 6, lane = t & 63;
    const int quad = lane >> 4, r = lane & 15;
    const int tensor = lane >> 5;
    const int n_local = lane & 31;

    const size_t qkv_base = (size_t)b * N_ * 1152;
    const int toff = 384 + tensor * 384 + h * 48;

    f32x4 acc[3][3] = {};
    bf16* kT = &stage[wave][0];
    bf16* vT = &stage[wave][1936];
    bf16* myT = &stage[wave][tensor * 1936];

    for (int c = wave; c < 25; c += 4) {
        int n0 = c * 32;
        bf16 rowbuf[48];
        if (n0 + n_local < N_) {
            const uint4* src = (const uint4*)(qkvb + qkv_base + (size_t)(n0 + n_local) * 1152 + toff);
            #pragma unroll
            for (int i = 0; i < 6; i++) *(uint4*)(&rowbuf[i * 8]) = src[i];
        } else {
            #pragma unroll
            for (int i = 0; i < 48; i++) rowbuf[i] = (bf16)0.f;
        }
        #pragma unroll
        for (int d = 0; d < 48; d++) myT[d * 40 + n_local] = rowbuf[d];
        bf16x8 af[3], bfv[3];
        #pragma unroll
        for (int i = 0; i < 3; i++) af[i]  = *(const bf16x8*)(&kT[(i * 16 + r) * 40 + quad * 8]);
        #pragma unroll
        for (int j = 0; j < 3; j++) bfv[j] = *(const bf16x8*)(&vT[(j * 16 + r) * 40 + quad * 8]);
        #pragma unroll
        for (int i = 0; i < 3; i++)
            #pragma unroll
            for (int j = 0; j < 3; j++)
                acc[i][j] = __builtin_amdgcn_mfma_f32_16x16x32_bf16(af[i], bfv[j], acc[i][j], 0, 0, 0);
    }

    #pragma unroll
    for (int i = 0; i < 3; i++)
        #pragma unroll
        for (int j = 0; j < 3; j++)
            #pragma unroll
            for (int e = 0; e < 4; e++)
                Sred[wave][i * 16 + quad * 4 + e][j * 16 + r] = acc[i][j][e];
    __syncthreads();

    if (t < 48) {
        float row[48];
        float mx = -1e30f;
        #pragma unroll
        for (int e = 0; e < 48; e++) {
            float s = Sred[0][t][e] + Sred[1][t][e] + Sred[2][t][e] + Sred[3][t][e];
            s *= 0.14433756729740644f;
            row[e] = s;
            mx = fmaxf(mx, s);
        }
        float sum = 0.f;
        #pragma unroll
        for (int e = 0; e < 48; e++) { float ex = __expf(row[e] - mx); row[e] = ex; sum += ex; }
        float inv = 1.f / sum;
        #pragma unroll
        for (int e = 0; e < 48; e++) attn_s[t * 72 + e] = (bf16)(row[e] * inv);
        #pragma unroll
        for (int e = 48; e < 64; e++) attn_s[t * 72 + e] = (bf16)0.f;
    }
    __syncthreads();

    const bf16* qbase = qkvb + qkv_base + h * 48;
    for (int nt = wave; nt < 49; nt += 4) {
        int n0 = nt * 16;
        f32x4 oacc[3] = {};
        #pragma unroll
        for (int kc = 0; kc < 2; kc++) {
            bf16x8 bq = *(const bf16x8*)(qbase + (size_t)(n0 + r) * 1152 + kc * 32 + quad * 8);
            #pragma unroll
            for (int i = 0; i < 3; i++) {
                bf16x8 aa = *(const bf16x8*)(&attn_s[(i * 16 + r) * 72 + kc * 32 + quad * 8]);
                oacc[i] = __builtin_amdgcn_mfma_f32_16x16x32_bf16(aa, bq, oacc[i], 0, 0, 0);
            }
        }
        #pragma unroll
        for (int i = 0; i < 3; i++) {
            bf16x4 ov;
            #pragma unroll
            for (int e = 0; e < 4; e++) ov[e] = (bf16)oacc[i][e];
            *(bf16x4*)(outp + (size_t)(b * N_ + n0 + r) * 384 + h * 48 + i * 16 + quad * 4) = ov;
        }
    }
}

// ---------------- launch ----------------
extern "C" void kernel_launch(void* const* d_in, const int* in_sizes, int n_in,
                              void* d_out, int out_size, void* d_ws, size_t ws_size,
                              hipStream_t stream) {
    const float* x      = (const float*)d_in[0];
    const float* cpe0_w = (const float*)d_in[3];
    const float* cpe0_b = (const float*)d_in[4];
    const float* cpe1_w = (const float*)d_in[5];
    const float* cpe1_b = (const float*)d_in[6];
    const float* n1g    = (const float*)d_in[7];
    const float* n1b    = (const float*)d_in[8];
    const float* qkv_w  = (const float*)d_in[9];
    const float* proj_w = (const float*)d_in[10];
    const float* proj_b = (const float*)d_in[11];
    const float* n2g    = (const float*)d_in[12];
    const float* n2b    = (const float*)d_in[13];
    const float* fc1_w  = (const float*)d_in[14];
    const float* fc1_b  = (const float*)d_in[15];
    const float* fc2_w  = (const float*)d_in[16];
    const float* fc2_b  = (const float*)d_in[17];

    char* ws = (char*)d_ws;
    size_t off = 0;
    bf16* cur    = (bf16*)(ws + off); off += (size_t)M_ * C_ * 2;
    bf16* qkvb   = (bf16*)(ws + off);
    float* x3    = (float*)qkvb;
    off += (size_t)M_ * 1152 * 2;
    bf16* hbuf   = (bf16*)(ws + off); off += (size_t)M_ * HID_ * 2;
    bf16* qkv_wb  = (bf16*)(ws + off); off += (size_t)1152 * 384 * 2;
    bf16* proj_wb = (bf16*)(ws + off); off += (size_t)384 * 384 * 2;
    bf16* fc1_wb  = (bf16*)(ws + off); off += (size_t)HID_ * 384 * 2;
    bf16* fc2_wb  = (bf16*)(ws + off); off += (size_t)384 * HID_ * 2;
    float* wt0    = (float*)(ws + off); off += (size_t)C_ * 9 * 4;
    float* wt1    = (float*)(ws + off); off += (size_t)C_ * 9 * 4;
    float* out = (float*)d_out;   // doubles as x1/x2 trunk buffer

    const int na = 442368, nb = 147456, nc = 589824, nd = 589824;
    convert4_kernel<<<(na + nb + nc + nd + 255) / 256, 256, 0, stream>>>(
        qkv_w, na, proj_w, nb, fc1_w, nc, fc2_w, nd, qkv_wb);
    wtrans_kernel<<<(C_ * 9 + 255) / 256, 256, 0, stream>>>(cpe0_w, cpe1_w, wt0, wt1);

    // CPE0 + LN1: x -> out (x1, fp32) and cur (bf16)
    cpe_ln_kernel<<<M_ / 4, 256, 0, stream>>>(x, wt0, cpe0_b, out, n1g, n1b, cur);
    // qkv: cur @ qkv_w^T -> qkvb  (M x 1152, K=384)
    gemm_kernel<false, false, false, true><<<dim3(1152 / 128, M_ / 128), 256, 0, stream>>>(
        cur, qkv_wb, nullptr, nullptr, qkvb, M_, 1152, 384);
    // fused channel attention -> cur
    attn_fused_kernel<<<256, 256, 0, stream>>>(qkvb, cur);
    // proj + bias + residual -> out (fp32)
    gemm_kernel<true, false, true, false><<<dim3(384 / 128, M_ / 128), 256, 0, stream>>>(
        cur, proj_wb, proj_b, out, out, M_, 384, 384);
    // CPE1 + LN2: out (x2) -> x3 (fp32) and cur (bf16)
    cpe_ln_kernel<<<M_ / 4, 256, 0, stream>>>(out, wt1, cpe1_b, x3, n2g, n2b, cur);
    // fc1 + bias + gelu -> hbuf (bf16), M x 1536, K=384
    gemm_kernel<true, true, false, true><<<dim3(HID_ / 128, M_ / 128), 256, 0, stream>>>(
        cur, fc1_wb, fc1_b, nullptr, hbuf, M_, HID_, 384);
    // fc2 + bias + residual x3 -> d_out (fp32), M x 384, K=1536
    gemm_kernel<true, false, true, false><<<dim3(384 / 128, M_ / 128), 256, 0, stream>>>(
        hbuf, fc2_wb, fc2_b, x3, out, M_, 384, HID_);
}